// Round 10
// baseline (302.492 us; speedup 1.0000x reference)
//
#include <hip/hip_runtime.h>
#include <hip/hip_bf16.h>
#include <stdint.h>

// SelfAttention B=8 H=8 S=2048 D=64 fp32, mask[B,S,S] int32 (0 -> -1e9).
// Round 10: OCCUPANCY — R6-R9 proved time invariant to LDS traffic/barriers/
// scheduling at 2 blocks/CU (latency-bound, MFMA 33%, VALU ~25%, rest idle).
// Cut LDS 64->32 KB (2 slots) + __launch_bounds__(512,8) => 4 blocks/CU,
// 32 waves/CU (8/SIMD), independent blocks provide cross-phase overlap.
// Keeps: max-free exp2 softmax, mask bias as MFMA C-in, K/V bf16 + mask
// bitpack prepass, gload_lds staging, ones-column denominator, setprio,
// XCD swizzle. vmcnt(0)+barrier per step (stage issued a full STEP early).

#define B_ 8
#define H_ 8
#define S_ 2048
#define D_ 64
#define QT 128  // q rows per block: 8 waves x 16
#define KT 64
#define NT (S_ / KT)
#define TILE_E (KT * D_)  // 4096 shorts = 8 KB per K (or V) slot
#define LOG2E 1.44269504088896340736f
#define QSCALE (0.125f * LOG2E)

typedef __bf16 bf16;
typedef bf16 bf16x8 __attribute__((ext_vector_type(8)));
typedef float f32x4 __attribute__((ext_vector_type(4)));
typedef unsigned short ushort8_t __attribute__((ext_vector_type(8)));
typedef unsigned long long u64;

#if __has_builtin(__builtin_amdgcn_exp2f)
#define EXP2(x) __builtin_amdgcn_exp2f(x)
#else
#define EXP2(x) exp2f(x)
#endif

static __device__ __forceinline__ unsigned short bfb(float f) {
    bf16 h = (bf16)f;  // RNE
    return __builtin_bit_cast(unsigned short, h);
}
// kv' bit-permutation: kv bits [b5 b4 b3 b2 b1 b0] -> kv' = [b5 b3 b2 b4 b1 b0].
static __device__ __forceinline__ int phi_inv(int c) {
    return ((c >> 5) & 1) * 32 + ((c >> 2) & 1) * 16 + ((c >> 4) & 1) * 8 +
           ((c >> 3) & 1) * 4 + (c & 3);
}
static __device__ __forceinline__ void gload16(const unsigned short* g, unsigned short* l) {
    __builtin_amdgcn_global_load_lds(
        (const __attribute__((address_space(1))) unsigned int*)g,
        (__attribute__((address_space(3))) unsigned int*)l, 16, 0, 0);
}

#define KV_BLOCKS (B_ * H_ * NT)  // 2048

// Fused prepass: blocks [0, KV_BLOCKS) convert K/V (if Ko != null); rest bitpack mask.
__global__ __launch_bounds__(256) void prep_fused(
    const float* __restrict__ K, const float* __restrict__ V,
    unsigned short* __restrict__ Ko, unsigned short* __restrict__ Vo,
    const int* __restrict__ M, u64* __restrict__ W) {
    const int tid = threadIdx.x;
    if (blockIdx.x >= KV_BLOCKS) {
        const int ln = tid & 63;
        const int w0 = (blockIdx.x - KV_BLOCKS) * 32 + (tid >> 6) * 8;
#pragma unroll
        for (int j = 0; j < 8; ++j) {
            const int v = M[(long)(w0 + j) * 64 + ln];
            const u64 bal = __ballot(v != 0);
            if (ln == 0) W[w0 + j] = bal;
        }
        return;
    }
    if (Ko == nullptr) return;
    __shared__ float Vl[64][65];
    const int t = blockIdx.x & (NT - 1);
    const int bh = blockIdx.x >> 5;
    const float* Kg = K + ((long)bh * S_ + t * 64) * D_;
    const float* Vg = V + ((long)bh * S_ + t * 64) * D_;
    unsigned short* Kout = Ko + ((long)bh * S_ + t * 64) * D_;
    unsigned short* Vout = Vo + (long)bh * D_ * S_ + t * 64;
    {   // K convert: 16 elems/thread
        const int kv = tid >> 2, d0 = (tid & 3) * 16;
#pragma unroll
        for (int half = 0; half < 2; ++half) {
            const float4 f0 = *(const float4*)(Kg + kv * D_ + d0 + half * 8);
            const float4 f1 = *(const float4*)(Kg + kv * D_ + d0 + half * 8 + 4);
            ushort8_t u;
            u[0] = bfb(f0.x); u[1] = bfb(f0.y); u[2] = bfb(f0.z); u[3] = bfb(f0.w);
            u[4] = bfb(f1.x); u[5] = bfb(f1.y); u[6] = bfb(f1.z); u[7] = bfb(f1.w);
            *(ushort8_t*)(Kout + kv * D_ + d0 + half * 8) = u;
        }
    }
    {   // V stage to LDS (coalesced reads)
#pragma unroll
        for (int i = 0; i < 4; ++i) {
            const int kv = i * 16 + (tid >> 4);
            const int d4 = (tid & 15) * 4;
            const float4 f = *(const float4*)(Vg + kv * D_ + d4);
            Vl[kv][d4 + 0] = f.x; Vl[kv][d4 + 1] = f.y;
            Vl[kv][d4 + 2] = f.z; Vl[kv][d4 + 3] = f.w;
        }
    }
    __syncthreads();
    {   // write transposed+permuted, coalesced ushort4 stores
#pragma unroll
        for (int j = 0; j < 4; ++j) {
            const int chunk = j * 256 + tid;
            const int d = chunk >> 4, q4 = chunk & 15;
            ushort4 w;
            w.x = bfb(Vl[phi_inv(q4 * 4 + 0)][d]);
            w.y = bfb(Vl[phi_inv(q4 * 4 + 1)][d]);
            w.z = bfb(Vl[phi_inv(q4 * 4 + 2)][d]);
            w.w = bfb(Vl[phi_inv(q4 * 4 + 3)][d]);
            *(ushort4*)(Vout + (long)d * S_ + q4 * 4) = w;
        }
    }
}

// ---- main kernel: 8 waves x 16 q-rows, 32 KB LDS (2 slots), 4 blocks/CU ----
__global__ __launch_bounds__(512, 8) void attn_main(
    const float* __restrict__ Q, const u64* __restrict__ W,
    const unsigned short* __restrict__ Kp, const unsigned short* __restrict__ Vp,
    float* __restrict__ O)
{
    __shared__ __attribute__((aligned(16))) unsigned short Ks2[2 * TILE_E];  // 16 KB
    __shared__ __attribute__((aligned(16))) unsigned short Vt2[2 * TILE_E];  // 16 KB

    const int tid = threadIdx.x;
    const int wv = tid >> 6, ln = tid & 63;
    const int col = ln & 15, grp = ln >> 4;

    int bid = blockIdx.x;
    bid = (bid & 7) * 128 + (bid >> 3);  // XCD chunk swizzle (1024 % 8 == 0, bijective)
    const int qt = bid & 15;
    const int h = (bid >> 4) & 7;
    const int b = bid >> 7;
    const int qw = qt * QT + wv * 16;

    // Q frag (B-operand): lane holds Q[q=col][d = c*32+grp*8+j] * QSCALE
    const float* Qg = Q + ((long)((b * H_ + h) * S_) + qw + col) * D_;
    bf16x8 qf[2];
#pragma unroll
    for (int c = 0; c < 2; ++c) {
        const float4 a0 = *(const float4*)(Qg + c * 32 + grp * 8);
        const float4 a1 = *(const float4*)(Qg + c * 32 + grp * 8 + 4);
        qf[c][0] = (bf16)(a0.x * QSCALE); qf[c][1] = (bf16)(a0.y * QSCALE);
        qf[c][2] = (bf16)(a0.z * QSCALE); qf[c][3] = (bf16)(a0.w * QSCALE);
        qf[c][4] = (bf16)(a1.x * QSCALE); qf[c][5] = (bf16)(a1.y * QSCALE);
        qf[c][6] = (bf16)(a1.z * QSCALE); qf[c][7] = (bf16)(a1.w * QSCALE);
    }
    bf16x8 onesf;
#pragma unroll
    for (int j = 0; j < 8; ++j) onesf[j] = (bf16)1.0f;

    f32x4 oacc[4];
#pragma unroll
    for (int i = 0; i < 4; ++i) oacc[i] = (f32x4){0.f, 0.f, 0.f, 0.f};
    f32x4 accs = (f32x4){0.f, 0.f, 0.f, 0.f};  // accs[r] = denominator for q=grp*4+r

    const u64* Wg = W + ((long)b * S_ + qw + col) * (S_ / 64);
    const unsigned short* Kbh = Kp + (long)(b * H_ + h) * S_ * D_;
    const unsigned short* Vbh = Vp + (long)(b * H_ + h) * D_ * S_;

    // gload addressing: 512 threads cover 64 rows x 128 B; linear LDS dest,
    // inverse-swizzled global source.
    const int srow = tid >> 3;            // 0..63
    const int rl = srow & 7;
    const int c8 = (tid & 7) ^ rl;

    auto STAGE_ISSUE = [&](int kv0, int buf) {  // 2 gload_lds/thread
        gload16(Kbh + (long)(kv0 + srow) * D_ + c8 * 8, Ks2 + buf * TILE_E + tid * 8);
        gload16(Vbh + (long)srow * S_ + kv0 + c8 * 8, Vt2 + buf * TILE_E + tid * 8);
    };

    auto STEP = [&](u64 mwfull, const unsigned short* Kc, const unsigned short* Vc) {
        // mask bias as MFMA C-in: 0 or -1e9
        f32x4 sc[4];
        {
            const u64 mws = mwfull >> (grp * 4);
            const unsigned mlo = (unsigned)mws, mhi = (unsigned)(mws >> 32);
#pragma unroll
            for (int blk = 0; blk < 4; ++blk) {
                const unsigned w32 = (blk < 2) ? mlo : mhi;
#pragma unroll
                for (int r = 0; r < 4; ++r) {
                    const int bit = (blk & 1) * 16 + r;  // compile-time
                    sc[blk][r] = ((w32 >> bit) & 1u) ? 0.0f : -1e9f;
                }
            }
        }
        // QK^T swapped (log2 domain): lane holds q=col, kv = blk*16 + grp*4 + r
        __builtin_amdgcn_s_setprio(1);
#pragma unroll
        for (int blk = 0; blk < 4; ++blk) {
            const int row = blk * 16 + col;
            const int byte0 = (row * 128 + grp * 16) ^ ((row & 7) << 4);
            const int byte1 = (row * 128 + 64 + grp * 16) ^ ((row & 7) << 4);
            const bf16x8 kf0 = *(const bf16x8*)((const char*)Kc + byte0);
            const bf16x8 kf1 = *(const bf16x8*)((const char*)Kc + byte1);
            sc[blk] = __builtin_amdgcn_mfma_f32_16x16x32_bf16(kf0, qf[0], sc[blk], 0, 0, 0);
            sc[blk] = __builtin_amdgcn_mfma_f32_16x16x32_bf16(kf1, qf[1], sc[blk], 0, 0, 0);
        }
        __builtin_amdgcn_s_setprio(0);
        // exp2 + bf16 pack (no max subtraction; masked -> exp2(-1e9) = 0)
        bf16x8 pf[2];
#pragma unroll
        for (int c = 0; c < 2; ++c)
#pragma unroll
            for (int j = 0; j < 8; ++j)
                pf[c][j] = (bf16)EXP2(sc[2 * c + (j >> 2)][j & 3]);
        // denominator + PV via MFMA
        __builtin_amdgcn_s_setprio(1);
        accs = __builtin_amdgcn_mfma_f32_16x16x32_bf16(pf[0], onesf, accs, 0, 0, 0);
        accs = __builtin_amdgcn_mfma_f32_16x16x32_bf16(pf[1], onesf, accs, 0, 0, 0);
#pragma unroll
        for (int c = 0; c < 2; ++c)
#pragma unroll
            for (int db = 0; db < 4; ++db) {
                const int vrow = db * 16 + col;
                const int byte = (vrow * 128 + c * 64 + grp * 16) ^ ((vrow & 7) << 4);
                const bf16x8 vf = *(const bf16x8*)((const char*)Vc + byte);
                oacc[db] = __builtin_amdgcn_mfma_f32_16x16x32_bf16(pf[c], vf, oacc[db], 0, 0, 0);
            }
        __builtin_amdgcn_s_setprio(0);
    };

#define WAIT0_BAR() do { asm volatile("s_waitcnt vmcnt(0)" ::: "memory"); \
    __builtin_amdgcn_s_barrier(); __builtin_amdgcn_sched_barrier(0); } while (0)

    // prologue: stage tile 0
    STAGE_ISSUE(0, 0);
    WAIT0_BAR();

#pragma unroll 1
    for (int t = 0; t < NT; t += 2) {  // NT = 32 even; slots compile-time
        {
            const u64 mw = Wg[t];
            if (t + 1 < NT) STAGE_ISSUE((t + 1) * KT, 1);
            STEP(mw, Ks2, Vt2);
            WAIT0_BAR();
        }
        {
            const u64 mw = Wg[t + 1];
            if (t + 2 < NT) STAGE_ISSUE((t + 2) * KT, 0);
            STEP(mw, Ks2 + TILE_E, Vt2 + TILE_E);
            WAIT0_BAR();
        }
    }

    // epilogue: accs[r] is the denominator, same layout as oacc — no shuffles
    float* Og = O + ((long)((b * H_ + h) * S_) + qw) * D_;
#pragma unroll
    for (int r = 0; r < 4; ++r) {
        const float inv = 1.0f / accs[r];
#pragma unroll
        for (int db = 0; db < 4; ++db)
            Og[(grp * 4 + r) * D_ + db * 16 + col] = oacc[db][r] * inv;
    }
#undef WAIT0_BAR
}

// ---- fallback kernel (512 thr, 16 q/wave, reg-staging, __syncthreads) ----
template <int MODE>
__global__ __launch_bounds__(512, 4) void attn_fb(
    const float* __restrict__ Q, const float* __restrict__ K,
    const float* __restrict__ V, const int* __restrict__ M,
    const u64* __restrict__ W, float* __restrict__ O)
{
    __shared__ __attribute__((aligned(16))) unsigned short Ks2[2 * TILE_E];
    __shared__ __attribute__((aligned(16))) unsigned short Vt2[2 * TILE_E];

    const int tid = threadIdx.x;
    const int wv = tid >> 6, ln = tid & 63;
    const int col = ln & 15, grp = ln >> 4;

    int bid = blockIdx.x;
    bid = (bid & 7) * 128 + (bid >> 3);
    const int qt = bid & 15;
    const int h = (bid >> 4) & 7;
    const int b = bid >> 7;
    const int qw = qt * 128 + wv * 16;

    const float* Qg = Q + ((long)((b * H_ + h) * S_) + qw + col) * D_;
    bf16x8 qf[2];
#pragma unroll
    for (int c = 0; c < 2; ++c) {
        const float4 a0 = *(const float4*)(Qg + c * 32 + grp * 8);
        const float4 a1 = *(const float4*)(Qg + c * 32 + grp * 8 + 4);
        qf[c][0] = (bf16)(a0.x * QSCALE); qf[c][1] = (bf16)(a0.y * QSCALE);
        qf[c][2] = (bf16)(a0.z * QSCALE); qf[c][3] = (bf16)(a0.w * QSCALE);
        qf[c][4] = (bf16)(a1.x * QSCALE); qf[c][5] = (bf16)(a1.y * QSCALE);
        qf[c][6] = (bf16)(a1.z * QSCALE); qf[c][7] = (bf16)(a1.w * QSCALE);
    }
    bf16x8 onesf;
#pragma unroll
    for (int j = 0; j < 8; ++j) onesf[j] = (bf16)1.0f;

    f32x4 oacc[4];
#pragma unroll
    for (int i = 0; i < 4; ++i) oacc[i] = (f32x4){0.f, 0.f, 0.f, 0.f};
    f32x4 accs = (f32x4){0.f, 0.f, 0.f, 0.f};

    const u64* Wg = (MODE >= 1) ? (W + ((long)b * S_ + qw + col) * (S_ / 64)) : nullptr;
    const int* Mg = (MODE == 0) ? (M + ((long)b * S_ + qw + col) * S_) : nullptr;
    const float* Kf = K + (long)(b * H_ + h) * S_ * D_;
    const float* Vf = V + (long)(b * H_ + h) * S_ * D_;

    float4 ka[2];
    float va[8];
    const int vd = ln, kg0 = wv;

    auto LOADT = [&](int kv0) {
#pragma unroll
        for (int i = 0; i < 2; ++i) {
            const int idx4 = i * 512 + tid;
            const int row = idx4 >> 4, c4 = idx4 & 15;
            ka[i] = *(const float4*)(Kf + (long)(kv0 + row) * D_ + c4 * 4);
        }
#pragma unroll
        for (int i = 0; i < 2; ++i) {
            const int kg = kg0 + i * 8;
            const int kvn = phi_inv(kg * 4);
#pragma unroll
            for (int j = 0; j < 4; ++j)
                va[i * 4 + j] = Vf[(long)(kv0 + kvn + j) * D_ + vd];
        }
    };
    auto WRITET = [&](int buf) {
#pragma unroll
        for (int i = 0; i < 2; ++i) {
            const int idx4 = i * 512 + tid;
            const int row = idx4 >> 4, c4 = idx4 & 15;
            const int byte = (row * 128 + c4 * 8) ^ ((row & 7) << 4);
            ushort4 w;
            w.x = bfb(ka[i].x); w.y = bfb(ka[i].y);
            w.z = bfb(ka[i].z); w.w = bfb(ka[i].w);
            *(ushort4*)((char*)(Ks2 + buf * TILE_E) + byte) = w;
        }
#pragma unroll
        for (int i = 0; i < 2; ++i) {
            const int kg = kg0 + i * 8;
            const int byte = (vd * 128 + kg * 8) ^ ((vd & 7) << 4);
            ushort4 w;
            w.x = bfb(va[i * 4 + 0]); w.y = bfb(va[i * 4 + 1]);
            w.z = bfb(va[i * 4 + 2]); w.w = bfb(va[i * 4 + 3]);
            *(ushort4*)((char*)(Vt2 + buf * TILE_E) + byte) = w;
        }
    };
    auto FSTEP = [&](u64 mwfull, int t, const unsigned short* Kc, const unsigned short* Vc) {
        f32x4 sc[4];
        const f32x4 zq = (f32x4){0.f, 0.f, 0.f, 0.f};
#pragma unroll
        for (int blk = 0; blk < 4; ++blk) {
            const int row = blk * 16 + col;
            const int byte0 = (row * 128 + grp * 16) ^ ((row & 7) << 4);
            const int byte1 = (row * 128 + 64 + grp * 16) ^ ((row & 7) << 4);
            const bf16x8 kf0 = *(const bf16x8*)((const char*)Kc + byte0);
            const bf16x8 kf1 = *(const bf16x8*)((const char*)Kc + byte1);
            sc[blk] = __builtin_amdgcn_mfma_f32_16x16x32_bf16(kf0, qf[0], zq, 0, 0, 0);
            sc[blk] = __builtin_amdgcn_mfma_f32_16x16x32_bf16(kf1, qf[1], sc[blk], 0, 0, 0);
        }
        bf16x8 pf[2];
        if (MODE >= 1) {
            const u64 mws = mwfull >> (grp * 4);
            const unsigned mlo = (unsigned)mws, mhi = (unsigned)(mws >> 32);
#pragma unroll
            for (int c = 0; c < 2; ++c)
#pragma unroll
                for (int j = 0; j < 8; ++j) {
                    const int blk = 2 * c + (j >> 2), r = j & 3;
                    const unsigned w32 = (blk < 2) ? mlo : mhi;
                    const int bit = (blk & 1) * 16 + r;
                    const float s = ((w32 >> bit) & 1u) ? sc[blk][r] : -1e9f;
                    pf[c][j] = (bf16)EXP2(s);
                }
        } else {
#pragma unroll
            for (int c = 0; c < 2; ++c)
#pragma unroll
                for (int j = 0; j < 8; ++j) {
                    const int blk = 2 * c + (j >> 2), r = j & 3;
                    const int mv = Mg[t * KT + blk * 16 + grp * 4 + r];
                    const float s = mv ? sc[blk][r] : -1e9f;
                    pf[c][j] = (bf16)EXP2(s);
                }
        }
        accs = __builtin_amdgcn_mfma_f32_16x16x32_bf16(pf[0], onesf, accs, 0, 0, 0);
        accs = __builtin_amdgcn_mfma_f32_16x16x32_bf16(pf[1], onesf, accs, 0, 0, 0);
#pragma unroll
        for (int c = 0; c < 2; ++c)
#pragma unroll
            for (int db = 0; db < 4; ++db) {
                const int vrow = db * 16 + col;
                const int byte = (vrow * 128 + c * 64 + grp * 16) ^ ((vrow & 7) << 4);
                const bf16x8 vf = *(const bf16x8*)((const char*)Vc + byte);
                oacc[db] = __builtin_amdgcn_mfma_f32_16x16x32_bf16(pf[c], vf, oacc[db], 0, 0, 0);
            }
    };

    LOADT(0);
    WRITET(0);
    __syncthreads();
#pragma unroll 1
    for (int t = 0; t < NT; t += 2) {
        if (t + 1 < NT) LOADT((t + 1) * KT);
        FSTEP(MODE >= 1 ? Wg[t] : 0ull, t, Ks2, Vt2);
        if (t + 1 < NT) WRITET(1);
        __syncthreads();
        if (t + 2 < NT) LOADT((t + 2) * KT);
        FSTEP(MODE >= 1 ? Wg[t + 1] : 0ull, t + 1, Ks2 + TILE_E, Vt2 + TILE_E);
        if (t + 2 < NT) WRITET(0);
        __syncthreads();
    }

    float* Og = O + ((long)((b * H_ + h) * S_) + qw) * D_;
#pragma unroll
    for (int r = 0; r < 4; ++r) {
        const float inv = 1.0f / accs[r];
#pragma unroll
        for (int db = 0; db < 4; ++db)
            Og[(grp * 4 + r) * D_ + db * 16 + col] = oacc[db][r] * inv;
    }
}

extern "C" void kernel_launch(void* const* d_in, const int* in_sizes, int n_in,
                              void* d_out, int out_size, void* d_ws, size_t ws_size,
                              hipStream_t stream) {
    (void)in_sizes; (void)n_in; (void)out_size;
    const float* Q = (const float*)d_in[0];
    const float* K = (const float*)d_in[1];
    const float* V = (const float*)d_in[2];
    const int*   M = (const int*)d_in[3];
    float* O = (float*)d_out;

    const size_t szW = (size_t)B_ * S_ * (S_ / 64) * sizeof(u64);      // 4 MB
    const size_t szK = (size_t)B_ * H_ * S_ * D_ * 2;                  // 16 MB
    const int nmaskblk = (B_ * S_ * (S_ / 64)) / 32;                   // 16384

    if (ws_size >= szW + 2 * szK) {
        u64* W = (u64*)d_ws;
        unsigned short* Kp = (unsigned short*)((char*)d_ws + szW);
        unsigned short* Vp = (unsigned short*)((char*)d_ws + szW + szK);
        prep_fused<<<KV_BLOCKS + nmaskblk, 256, 0, stream>>>(K, V, Kp, Vp, M, W);
        attn_main<<<B_ * H_ * (S_ / QT), 512, 0, stream>>>(Q, W, Kp, Vp, O);  // 1024 blocks
    } else if (ws_size >= szW) {
        u64* W = (u64*)d_ws;
        prep_fused<<<KV_BLOCKS + nmaskblk, 256, 0, stream>>>(K, V, nullptr, nullptr, M, W);
        attn_fb<1><<<1024, 512, 0, stream>>>(Q, K, V, M, W, O);
    } else {
        attn_fb<0><<<1024, 512, 0, stream>>>(Q, K, V, M, nullptr, O);
    }
}

// Round 11
// 291.654 us; speedup vs baseline: 1.0372x; 1.0372x over previous
//
#include <hip/hip_runtime.h>
#include <hip/hip_bf16.h>
#include <stdint.h>

// SelfAttention B=8 H=8 S=2048 D=64 fp32, mask[B,S,S] int32 (0 -> -1e9).
// Round 11: register diet -> true 8 waves/SIMD. R10 proved: (a) occupancy was
// reg-capped at 4 waves/SIMD all along (arch+acc total 65-128; VGPR_Count is
// arch-only), (b) 4 blocks/CU co-reside at 32 KB LDS when regs fit, (c) forcing
// <=64 without a diet spills ~1GB. Diet: two-half QK (sc acc 16->8), denominator
// via VALU dsum (drop ones-MFMA: -4 acc, -4 arch). Total ~60 <= 64.
// Keeps: max-free exp2 softmax, select masking, K/V bf16 + mask bitpack prepass,
// gload_lds staging, setprio, XCD swizzle, 2 LDS slots + vmcnt(0) barriers.

#define B_ 8
#define H_ 8
#define S_ 2048
#define D_ 64
#define QT 128  // q rows per block: 8 waves x 16
#define KT 64
#define NT (S_ / KT)
#define TILE_E (KT * D_)  // 4096 shorts = 8 KB per K (or V) slot
#define LOG2E 1.44269504088896340736f
#define QSCALE (0.125f * LOG2E)

typedef __bf16 bf16;
typedef bf16 bf16x8 __attribute__((ext_vector_type(8)));
typedef float f32x4 __attribute__((ext_vector_type(4)));
typedef unsigned short ushort8_t __attribute__((ext_vector_type(8)));
typedef unsigned long long u64;

#if __has_builtin(__builtin_amdgcn_exp2f)
#define EXP2(x) __builtin_amdgcn_exp2f(x)
#else
#define EXP2(x) exp2f(x)
#endif

static __device__ __forceinline__ unsigned short bfb(float f) {
    bf16 h = (bf16)f;  // RNE
    return __builtin_bit_cast(unsigned short, h);
}
// kv' bit-permutation: kv bits [b5 b4 b3 b2 b1 b0] -> kv' = [b5 b3 b2 b4 b1 b0].
static __device__ __forceinline__ int phi_inv(int c) {
    return ((c >> 5) & 1) * 32 + ((c >> 2) & 1) * 16 + ((c >> 4) & 1) * 8 +
           ((c >> 3) & 1) * 4 + (c & 3);
}
static __device__ __forceinline__ void gload16(const unsigned short* g, unsigned short* l) {
    __builtin_amdgcn_global_load_lds(
        (const __attribute__((address_space(1))) unsigned int*)g,
        (__attribute__((address_space(3))) unsigned int*)l, 16, 0, 0);
}

#define KV_BLOCKS (B_ * H_ * NT)  // 2048

// Fused prepass: blocks [0, KV_BLOCKS) convert K/V (if Ko != null); rest bitpack mask.
__global__ __launch_bounds__(256) void prep_fused(
    const float* __restrict__ K, const float* __restrict__ V,
    unsigned short* __restrict__ Ko, unsigned short* __restrict__ Vo,
    const int* __restrict__ M, u64* __restrict__ W) {
    const int tid = threadIdx.x;
    if (blockIdx.x >= KV_BLOCKS) {
        const int ln = tid & 63;
        const int w0 = (blockIdx.x - KV_BLOCKS) * 32 + (tid >> 6) * 8;
#pragma unroll
        for (int j = 0; j < 8; ++j) {
            const int v = M[(long)(w0 + j) * 64 + ln];
            const u64 bal = __ballot(v != 0);
            if (ln == 0) W[w0 + j] = bal;
        }
        return;
    }
    if (Ko == nullptr) return;
    __shared__ float Vl[64][65];
    const int t = blockIdx.x & (NT - 1);
    const int bh = blockIdx.x >> 5;
    const float* Kg = K + ((long)bh * S_ + t * 64) * D_;
    const float* Vg = V + ((long)bh * S_ + t * 64) * D_;
    unsigned short* Kout = Ko + ((long)bh * S_ + t * 64) * D_;
    unsigned short* Vout = Vo + (long)bh * D_ * S_ + t * 64;
    {   // K convert: 16 elems/thread
        const int kv = tid >> 2, d0 = (tid & 3) * 16;
#pragma unroll
        for (int half = 0; half < 2; ++half) {
            const float4 f0 = *(const float4*)(Kg + kv * D_ + d0 + half * 8);
            const float4 f1 = *(const float4*)(Kg + kv * D_ + d0 + half * 8 + 4);
            ushort8_t u;
            u[0] = bfb(f0.x); u[1] = bfb(f0.y); u[2] = bfb(f0.z); u[3] = bfb(f0.w);
            u[4] = bfb(f1.x); u[5] = bfb(f1.y); u[6] = bfb(f1.z); u[7] = bfb(f1.w);
            *(ushort8_t*)(Kout + kv * D_ + d0 + half * 8) = u;
        }
    }
    {   // V stage to LDS (coalesced reads)
#pragma unroll
        for (int i = 0; i < 4; ++i) {
            const int kv = i * 16 + (tid >> 4);
            const int d4 = (tid & 15) * 4;
            const float4 f = *(const float4*)(Vg + kv * D_ + d4);
            Vl[kv][d4 + 0] = f.x; Vl[kv][d4 + 1] = f.y;
            Vl[kv][d4 + 2] = f.z; Vl[kv][d4 + 3] = f.w;
        }
    }
    __syncthreads();
    {   // write transposed+permuted, coalesced ushort4 stores
#pragma unroll
        for (int j = 0; j < 4; ++j) {
            const int chunk = j * 256 + tid;
            const int d = chunk >> 4, q4 = chunk & 15;
            ushort4 w;
            w.x = bfb(Vl[phi_inv(q4 * 4 + 0)][d]);
            w.y = bfb(Vl[phi_inv(q4 * 4 + 1)][d]);
            w.z = bfb(Vl[phi_inv(q4 * 4 + 2)][d]);
            w.w = bfb(Vl[phi_inv(q4 * 4 + 3)][d]);
            *(ushort4*)(Vout + (long)d * S_ + q4 * 4) = w;
        }
    }
}

// ---- main kernel: 8 waves x 16 q-rows, 32 KB LDS, total regs <= 64 => 8 waves/SIMD ----
__global__ __launch_bounds__(512, 8) void attn_main(
    const float* __restrict__ Q, const u64* __restrict__ W,
    const unsigned short* __restrict__ Kp, const unsigned short* __restrict__ Vp,
    float* __restrict__ O)
{
    __shared__ __attribute__((aligned(16))) unsigned short Ks2[2 * TILE_E];  // 16 KB
    __shared__ __attribute__((aligned(16))) unsigned short Vt2[2 * TILE_E];  // 16 KB

    const int tid = threadIdx.x;
    const int wv = tid >> 6, ln = tid & 63;
    const int col = ln & 15, grp = ln >> 4;

    int bid = blockIdx.x;
    bid = (bid & 7) * 128 + (bid >> 3);  // XCD chunk swizzle (1024 % 8 == 0, bijective)
    const int qt = bid & 15;
    const int h = (bid >> 4) & 7;
    const int b = bid >> 7;
    const int qw = qt * QT + wv * 16;

    // Q frag (B-operand): lane holds Q[q=col][d = c*32+grp*8+j] * QSCALE
    const float* Qg = Q + ((long)((b * H_ + h) * S_) + qw + col) * D_;
    bf16x8 qf[2];
#pragma unroll
    for (int c = 0; c < 2; ++c) {
        const float4 a0 = *(const float4*)(Qg + c * 32 + grp * 8);
        const float4 a1 = *(const float4*)(Qg + c * 32 + grp * 8 + 4);
        qf[c][0] = (bf16)(a0.x * QSCALE); qf[c][1] = (bf16)(a0.y * QSCALE);
        qf[c][2] = (bf16)(a0.z * QSCALE); qf[c][3] = (bf16)(a0.w * QSCALE);
        qf[c][4] = (bf16)(a1.x * QSCALE); qf[c][5] = (bf16)(a1.y * QSCALE);
        qf[c][6] = (bf16)(a1.z * QSCALE); qf[c][7] = (bf16)(a1.w * QSCALE);
    }

    f32x4 oacc[4];
#pragma unroll
    for (int i = 0; i < 4; ++i) oacc[i] = (f32x4){0.f, 0.f, 0.f, 0.f};
    float dsum = 0.f;  // per-lane partial denominator for q-row = col

    const u64* Wg = W + ((long)b * S_ + qw + col) * (S_ / 64);
    const unsigned short* Kbh = Kp + (long)(b * H_ + h) * S_ * D_;
    const unsigned short* Vbh = Vp + (long)(b * H_ + h) * D_ * S_;

    // gload addressing: 512 threads cover 64 rows x 128 B; linear LDS dest,
    // inverse-swizzled global source.
    const int srow = tid >> 3;            // 0..63
    const int c8 = (tid & 7) ^ (srow & 7);

    auto STAGE_ISSUE = [&](int kv0, int buf) {  // 2 gload_lds/thread
        gload16(Kbh + (long)(kv0 + srow) * D_ + c8 * 8, Ks2 + buf * TILE_E + tid * 8);
        gload16(Vbh + (long)srow * S_ + kv0 + c8 * 8, Vt2 + buf * TILE_E + tid * 8);
    };

    const f32x4 zq = (f32x4){0.f, 0.f, 0.f, 0.f};

    auto STEP = [&](u64 mwfull, const unsigned short* Kc, const unsigned short* Vc) {
        const u64 mws = mwfull >> (grp * 4);
        const unsigned mlo = (unsigned)mws, mhi = (unsigned)(mws >> 32);
        bf16x8 pf[2];
        // Two-half QK: sc regs (8 acc) reused across halves -> low register peak
#pragma unroll
        for (int half = 0; half < 2; ++half) {
            const unsigned mw32 = half ? mhi : mlo;
            f32x4 sc[2];
            __builtin_amdgcn_s_setprio(1);
#pragma unroll
            for (int bb = 0; bb < 2; ++bb) {
                const int row = (half * 2 + bb) * 16 + col;
                const int byte0 = (row * 128 + grp * 16) ^ ((row & 7) << 4);
                const int byte1 = (row * 128 + 64 + grp * 16) ^ ((row & 7) << 4);
                const bf16x8 kf0 = *(const bf16x8*)((const char*)Kc + byte0);
                const bf16x8 kf1 = *(const bf16x8*)((const char*)Kc + byte1);
                sc[bb] = __builtin_amdgcn_mfma_f32_16x16x32_bf16(kf0, qf[0], zq, 0, 0, 0);
                sc[bb] = __builtin_amdgcn_mfma_f32_16x16x32_bf16(kf1, qf[1], sc[bb], 0, 0, 0);
            }
            __builtin_amdgcn_s_setprio(0);
            // select + exp2 + pack; denominator accumulated in VALU (no ones-MFMA)
#pragma unroll
            for (int j = 0; j < 8; ++j) {
                const int bb = j >> 2, r = j & 3;
                const int bit = bb * 16 + r;  // compile-time
                const float s = ((mw32 >> bit) & 1u) ? sc[bb][r] : -1e9f;
                const float e = EXP2(s);
                dsum += e;
                pf[half][j] = (bf16)e;
            }
        }
        // PV
        __builtin_amdgcn_s_setprio(1);
#pragma unroll
        for (int c = 0; c < 2; ++c)
#pragma unroll
            for (int db = 0; db < 4; ++db) {
                const int vrow = db * 16 + col;
                const int byte = (vrow * 128 + c * 64 + grp * 16) ^ ((vrow & 7) << 4);
                const bf16x8 vf = *(const bf16x8*)((const char*)Vc + byte);
                oacc[db] = __builtin_amdgcn_mfma_f32_16x16x32_bf16(pf[c], vf, oacc[db], 0, 0, 0);
            }
        __builtin_amdgcn_s_setprio(0);
    };

#define WAIT0_BAR() do { asm volatile("s_waitcnt vmcnt(0)" ::: "memory"); \
    __builtin_amdgcn_s_barrier(); __builtin_amdgcn_sched_barrier(0); } while (0)

    // prologue: stage tile 0
    STAGE_ISSUE(0, 0);
    WAIT0_BAR();

#pragma unroll 1
    for (int t = 0; t < NT; t += 2) {  // NT = 32 even; slots compile-time
        {
            const u64 mw = Wg[t];
            if (t + 1 < NT) STAGE_ISSUE((t + 1) * KT, 1);
            STEP(mw, Ks2, Vt2);
            WAIT0_BAR();
        }
        {
            const u64 mw = Wg[t + 1];
            if (t + 2 < NT) STAGE_ISSUE((t + 2) * KT, 0);
            STEP(mw, Ks2 + TILE_E, Vt2 + TILE_E);
            WAIT0_BAR();
        }
    }

    // epilogue: reduce dsum across the 4 lane-replicas, broadcast per output row
    dsum += __shfl_xor(dsum, 16);
    dsum += __shfl_xor(dsum, 32);
    float* Og = O + ((long)((b * H_ + h) * S_) + qw) * D_;
#pragma unroll
    for (int r = 0; r < 4; ++r) {
        const float inv = 1.0f / __shfl(dsum, grp * 20 + r);  // lane with col == grp*4+r
#pragma unroll
        for (int db = 0; db < 4; ++db)
            Og[(grp * 4 + r) * D_ + db * 16 + col] = oacc[db][r] * inv;
    }
#undef WAIT0_BAR
}

// ---- fallback kernel (512 thr, 16 q/wave, reg-staging, __syncthreads) ----
template <int MODE>
__global__ __launch_bounds__(512, 4) void attn_fb(
    const float* __restrict__ Q, const float* __restrict__ K,
    const float* __restrict__ V, const int* __restrict__ M,
    const u64* __restrict__ W, float* __restrict__ O)
{
    __shared__ __attribute__((aligned(16))) unsigned short Ks2[2 * TILE_E];
    __shared__ __attribute__((aligned(16))) unsigned short Vt2[2 * TILE_E];

    const int tid = threadIdx.x;
    const int wv = tid >> 6, ln = tid & 63;
    const int col = ln & 15, grp = ln >> 4;

    int bid = blockIdx.x;
    bid = (bid & 7) * 128 + (bid >> 3);
    const int qt = bid & 15;
    const int h = (bid >> 4) & 7;
    const int b = bid >> 7;
    const int qw = qt * 128 + wv * 16;

    const float* Qg = Q + ((long)((b * H_ + h) * S_) + qw + col) * D_;
    bf16x8 qf[2];
#pragma unroll
    for (int c = 0; c < 2; ++c) {
        const float4 a0 = *(const float4*)(Qg + c * 32 + grp * 8);
        const float4 a1 = *(const float4*)(Qg + c * 32 + grp * 8 + 4);
        qf[c][0] = (bf16)(a0.x * QSCALE); qf[c][1] = (bf16)(a0.y * QSCALE);
        qf[c][2] = (bf16)(a0.z * QSCALE); qf[c][3] = (bf16)(a0.w * QSCALE);
        qf[c][4] = (bf16)(a1.x * QSCALE); qf[c][5] = (bf16)(a1.y * QSCALE);
        qf[c][6] = (bf16)(a1.z * QSCALE); qf[c][7] = (bf16)(a1.w * QSCALE);
    }
    bf16x8 onesf;
#pragma unroll
    for (int j = 0; j < 8; ++j) onesf[j] = (bf16)1.0f;

    f32x4 oacc[4];
#pragma unroll
    for (int i = 0; i < 4; ++i) oacc[i] = (f32x4){0.f, 0.f, 0.f, 0.f};
    f32x4 accs = (f32x4){0.f, 0.f, 0.f, 0.f};

    const u64* Wg = (MODE >= 1) ? (W + ((long)b * S_ + qw + col) * (S_ / 64)) : nullptr;
    const int* Mg = (MODE == 0) ? (M + ((long)b * S_ + qw + col) * S_) : nullptr;
    const float* Kf = K + (long)(b * H_ + h) * S_ * D_;
    const float* Vf = V + (long)(b * H_ + h) * S_ * D_;

    float4 ka[2];
    float va[8];
    const int vd = ln, kg0 = wv;

    auto LOADT = [&](int kv0) {
#pragma unroll
        for (int i = 0; i < 2; ++i) {
            const int idx4 = i * 512 + tid;
            const int row = idx4 >> 4, c4 = idx4 & 15;
            ka[i] = *(const float4*)(Kf + (long)(kv0 + row) * D_ + c4 * 4);
        }
#pragma unroll
        for (int i = 0; i < 2; ++i) {
            const int kg = kg0 + i * 8;
            const int kvn = phi_inv(kg * 4);
#pragma unroll
            for (int j = 0; j < 4; ++j)
                va[i * 4 + j] = Vf[(long)(kv0 + kvn + j) * D_ + vd];
        }
    };
    auto WRITET = [&](int buf) {
#pragma unroll
        for (int i = 0; i < 2; ++i) {
            const int idx4 = i * 512 + tid;
            const int row = idx4 >> 4, c4 = idx4 & 15;
            const int byte = (row * 128 + c4 * 8) ^ ((row & 7) << 4);
            ushort4 w;
            w.x = bfb(ka[i].x); w.y = bfb(ka[i].y);
            w.z = bfb(ka[i].z); w.w = bfb(ka[i].w);
            *(ushort4*)((char*)(Ks2 + buf * TILE_E) + byte) = w;
        }
#pragma unroll
        for (int i = 0; i < 2; ++i) {
            const int kg = kg0 + i * 8;
            const int byte = (vd * 128 + kg * 8) ^ ((vd & 7) << 4);
            ushort4 w;
            w.x = bfb(va[i * 4 + 0]); w.y = bfb(va[i * 4 + 1]);
            w.z = bfb(va[i * 4 + 2]); w.w = bfb(va[i * 4 + 3]);
            *(ushort4*)((char*)(Vt2 + buf * TILE_E) + byte) = w;
        }
    };
    auto FSTEP = [&](u64 mwfull, int t, const unsigned short* Kc, const unsigned short* Vc) {
        f32x4 sc[4];
        const f32x4 zq = (f32x4){0.f, 0.f, 0.f, 0.f};
#pragma unroll
        for (int blk = 0; blk < 4; ++blk) {
            const int row = blk * 16 + col;
            const int byte0 = (row * 128 + grp * 16) ^ ((row & 7) << 4);
            const int byte1 = (row * 128 + 64 + grp * 16) ^ ((row & 7) << 4);
            const bf16x8 kf0 = *(const bf16x8*)((const char*)Kc + byte0);
            const bf16x8 kf1 = *(const bf16x8*)((const char*)Kc + byte1);
            sc[blk] = __builtin_amdgcn_mfma_f32_16x16x32_bf16(kf0, qf[0], zq, 0, 0, 0);
            sc[blk] = __builtin_amdgcn_mfma_f32_16x16x32_bf16(kf1, qf[1], sc[blk], 0, 0, 0);
        }
        bf16x8 pf[2];
        if (MODE >= 1) {
            const u64 mws = mwfull >> (grp * 4);
            const unsigned mlo = (unsigned)mws, mhi = (unsigned)(mws >> 32);
#pragma unroll
            for (int c = 0; c < 2; ++c)
#pragma unroll
                for (int j = 0; j < 8; ++j) {
                    const int blk = 2 * c + (j >> 2), r = j & 3;
                    const unsigned w32 = (blk < 2) ? mlo : mhi;
                    const int bit = (blk & 1) * 16 + r;
                    const float s = ((w32 >> bit) & 1u) ? sc[blk][r] : -1e9f;
                    pf[c][j] = (bf16)EXP2(s);
                }
        } else {
#pragma unroll
            for (int c = 0; c < 2; ++c)
#pragma unroll
                for (int j = 0; j < 8; ++j) {
                    const int blk = 2 * c + (j >> 2), r = j & 3;
                    const int mv = Mg[t * KT + blk * 16 + grp * 4 + r];
                    const float s = mv ? sc[blk][r] : -1e9f;
                    pf[c][j] = (bf16)EXP2(s);
                }
        }
        accs = __builtin_amdgcn_mfma_f32_16x16x32_bf16(pf[0], onesf, accs, 0, 0, 0);
        accs = __builtin_amdgcn_mfma_f32_16x16x32_bf16(pf[1], onesf, accs, 0, 0, 0);
#pragma unroll
        for (int c = 0; c < 2; ++c)
#pragma unroll
            for (int db = 0; db < 4; ++db) {
                const int vrow = db * 16 + col;
                const int byte = (vrow * 128 + c * 64 + grp * 16) ^ ((vrow & 7) << 4);
                const bf16x8 vf = *(const bf16x8*)((const char*)Vc + byte);
                oacc[db] = __builtin_amdgcn_mfma_f32_16x16x32_bf16(pf[c], vf, oacc[db], 0, 0, 0);
            }
    };

    LOADT(0);
    WRITET(0);
    __syncthreads();
#pragma unroll 1
    for (int t = 0; t < NT; t += 2) {
        if (t + 1 < NT) LOADT((t + 1) * KT);
        FSTEP(MODE >= 1 ? Wg[t] : 0ull, t, Ks2, Vt2);
        if (t + 1 < NT) WRITET(1);
        __syncthreads();
        if (t + 2 < NT) LOADT((t + 2) * KT);
        FSTEP(MODE >= 1 ? Wg[t + 1] : 0ull, t + 1, Ks2 + TILE_E, Vt2 + TILE_E);
        if (t + 2 < NT) WRITET(0);
        __syncthreads();
    }

    float* Og = O + ((long)((b * H_ + h) * S_) + qw) * D_;
#pragma unroll
    for (int r = 0; r < 4; ++r) {
        const float inv = 1.0f / accs[r];
#pragma unroll
        for (int db = 0; db < 4; ++db)
            Og[(grp * 4 + r) * D_ + db * 16 + col] = oacc[db][r] * inv;
    }
}

extern "C" void kernel_launch(void* const* d_in, const int* in_sizes, int n_in,
                              void* d_out, int out_size, void* d_ws, size_t ws_size,
                              hipStream_t stream) {
    (void)in_sizes; (void)n_in; (void)out_size;
    const float* Q = (const float*)d_in[0];
    const float* K = (const float*)d_in[1];
    const float* V = (const float*)d_in[2];
    const int*   M = (const int*)d_in[3];
    float* O = (float*)d_out;

    const size_t szW = (size_t)B_ * S_ * (S_ / 64) * sizeof(u64);      // 4 MB
    const size_t szK = (size_t)B_ * H_ * S_ * D_ * 2;                  // 16 MB
    const int nmaskblk = (B_ * S_ * (S_ / 64)) / 32;                   // 16384

    if (ws_size >= szW + 2 * szK) {
        u64* W = (u64*)d_ws;
        unsigned short* Kp = (unsigned short*)((char*)d_ws + szW);
        unsigned short* Vp = (unsigned short*)((char*)d_ws + szW + szK);
        prep_fused<<<KV_BLOCKS + nmaskblk, 256, 0, stream>>>(K, V, Kp, Vp, M, W);
        attn_main<<<B_ * H_ * (S_ / QT), 512, 0, stream>>>(Q, W, Kp, Vp, O);  // 1024 blocks
    } else if (ws_size >= szW) {
        u64* W = (u64*)d_ws;
        prep_fused<<<KV_BLOCKS + nmaskblk, 256, 0, stream>>>(K, V, nullptr, nullptr, M, W);
        attn_fb<1><<<1024, 512, 0, stream>>>(Q, K, V, M, W, O);
    } else {
        attn_fb<0><<<1024, 512, 0, stream>>>(Q, K, V, M, nullptr, O);
    }
}

// Round 12
// 195.593 us; speedup vs baseline: 1.5465x; 1.4911x over previous
//
#include <hip/hip_runtime.h>
#include <hip/hip_bf16.h>
#include <stdint.h>

// SelfAttention B=8 H=8 S=2048 D=64 fp32, mask[B,S,S] int32 (0 -> -1e9).
// Round 12: 4 independent barrier groups per CU. 256-thr blocks (4 waves),
// dual q-subtile (32 q/wave, QT=128), 2 LDS slots (32 KB) -> 4 blocks/CU,
// 16 waves/CU in 4 groups (phase decorrelation). launch_bounds(256,4) = 128-reg
// cap, denominator via VALU dsum (frees 8 acc + 4 arch regs, no spill).
// Keeps: max-free exp2 softmax, mask bias as MFMA C-in, K/V bf16 + mask
// bitpack prepass, gload_lds staging, setprio, XCD swizzle, vmcnt(0) barriers.

#define B_ 8
#define H_ 8
#define S_ 2048
#define D_ 64
#define QT 128  // q rows per block: 4 waves x 32
#define KT 64
#define NT (S_ / KT)
#define TILE_E (KT * D_)  // 4096 shorts = 8 KB per K (or V) slot
#define LOG2E 1.44269504088896340736f
#define QSCALE (0.125f * LOG2E)

typedef __bf16 bf16;
typedef bf16 bf16x8 __attribute__((ext_vector_type(8)));
typedef float f32x4 __attribute__((ext_vector_type(4)));
typedef unsigned short ushort8_t __attribute__((ext_vector_type(8)));
typedef unsigned long long u64;

#if __has_builtin(__builtin_amdgcn_exp2f)
#define EXP2(x) __builtin_amdgcn_exp2f(x)
#else
#define EXP2(x) exp2f(x)
#endif

static __device__ __forceinline__ unsigned short bfb(float f) {
    bf16 h = (bf16)f;  // RNE
    return __builtin_bit_cast(unsigned short, h);
}
// kv' bit-permutation: kv bits [b5 b4 b3 b2 b1 b0] -> kv' = [b5 b3 b2 b4 b1 b0].
static __device__ __forceinline__ int phi_inv(int c) {
    return ((c >> 5) & 1) * 32 + ((c >> 2) & 1) * 16 + ((c >> 4) & 1) * 8 +
           ((c >> 3) & 1) * 4 + (c & 3);
}
static __device__ __forceinline__ void gload16(const unsigned short* g, unsigned short* l) {
    __builtin_amdgcn_global_load_lds(
        (const __attribute__((address_space(1))) unsigned int*)g,
        (__attribute__((address_space(3))) unsigned int*)l, 16, 0, 0);
}

#define KV_BLOCKS (B_ * H_ * NT)  // 2048

// Fused prepass: blocks [0, KV_BLOCKS) convert K/V (if Ko != null); rest bitpack mask.
__global__ __launch_bounds__(256) void prep_fused(
    const float* __restrict__ K, const float* __restrict__ V,
    unsigned short* __restrict__ Ko, unsigned short* __restrict__ Vo,
    const int* __restrict__ M, u64* __restrict__ W) {
    const int tid = threadIdx.x;
    if (blockIdx.x >= KV_BLOCKS) {
        const int ln = tid & 63;
        const int w0 = (blockIdx.x - KV_BLOCKS) * 32 + (tid >> 6) * 8;
#pragma unroll
        for (int j = 0; j < 8; ++j) {
            const int v = M[(long)(w0 + j) * 64 + ln];
            const u64 bal = __ballot(v != 0);
            if (ln == 0) W[w0 + j] = bal;
        }
        return;
    }
    if (Ko == nullptr) return;
    __shared__ float Vl[64][65];
    const int t = blockIdx.x & (NT - 1);
    const int bh = blockIdx.x >> 5;
    const float* Kg = K + ((long)bh * S_ + t * 64) * D_;
    const float* Vg = V + ((long)bh * S_ + t * 64) * D_;
    unsigned short* Kout = Ko + ((long)bh * S_ + t * 64) * D_;
    unsigned short* Vout = Vo + (long)bh * D_ * S_ + t * 64;
    {   // K convert: 16 elems/thread
        const int kv = tid >> 2, d0 = (tid & 3) * 16;
#pragma unroll
        for (int half = 0; half < 2; ++half) {
            const float4 f0 = *(const float4*)(Kg + kv * D_ + d0 + half * 8);
            const float4 f1 = *(const float4*)(Kg + kv * D_ + d0 + half * 8 + 4);
            ushort8_t u;
            u[0] = bfb(f0.x); u[1] = bfb(f0.y); u[2] = bfb(f0.z); u[3] = bfb(f0.w);
            u[4] = bfb(f1.x); u[5] = bfb(f1.y); u[6] = bfb(f1.z); u[7] = bfb(f1.w);
            *(ushort8_t*)(Kout + kv * D_ + d0 + half * 8) = u;
        }
    }
    {   // V stage to LDS (coalesced reads)
#pragma unroll
        for (int i = 0; i < 4; ++i) {
            const int kv = i * 16 + (tid >> 4);
            const int d4 = (tid & 15) * 4;
            const float4 f = *(const float4*)(Vg + kv * D_ + d4);
            Vl[kv][d4 + 0] = f.x; Vl[kv][d4 + 1] = f.y;
            Vl[kv][d4 + 2] = f.z; Vl[kv][d4 + 3] = f.w;
        }
    }
    __syncthreads();
    {   // write transposed+permuted, coalesced ushort4 stores
#pragma unroll
        for (int j = 0; j < 4; ++j) {
            const int chunk = j * 256 + tid;
            const int d = chunk >> 4, q4 = chunk & 15;
            ushort4 w;
            w.x = bfb(Vl[phi_inv(q4 * 4 + 0)][d]);
            w.y = bfb(Vl[phi_inv(q4 * 4 + 1)][d]);
            w.z = bfb(Vl[phi_inv(q4 * 4 + 2)][d]);
            w.w = bfb(Vl[phi_inv(q4 * 4 + 3)][d]);
            *(ushort4*)(Vout + (long)d * S_ + q4 * 4) = w;
        }
    }
}

// ---- main: 4 waves x 32 q-rows (dual subtile), 32 KB LDS, 4 blocks/CU ----
__global__ __launch_bounds__(256, 4) void attn_main(
    const float* __restrict__ Q, const u64* __restrict__ W,
    const unsigned short* __restrict__ Kp, const unsigned short* __restrict__ Vp,
    float* __restrict__ O)
{
    __shared__ __attribute__((aligned(16))) unsigned short Ks2[2 * TILE_E];  // 16 KB
    __shared__ __attribute__((aligned(16))) unsigned short Vt2[2 * TILE_E];  // 16 KB

    const int tid = threadIdx.x;
    const int wv = tid >> 6, ln = tid & 63;
    const int col = ln & 15, grp = ln >> 4;

    int bid = blockIdx.x;
    bid = (bid & 7) * 128 + (bid >> 3);  // XCD chunk swizzle (1024 % 8 == 0, bijective)
    const int qt = bid & 15;
    const int h = (bid >> 4) & 7;
    const int b = bid >> 7;
    const int qa = qt * QT + wv * 32;    // subtile a: rows qa..qa+15; b: qa+16..qa+31

    // Q frags (B-operand) for both subtiles, prescaled
    bf16x8 qfa[2], qfb[2];
    {
        const float* Qga = Q + ((long)((b * H_ + h) * S_) + qa + col) * D_;
        const float* Qgb = Qga + 16 * D_;
#pragma unroll
        for (int c = 0; c < 2; ++c) {
            const float4 a0 = *(const float4*)(Qga + c * 32 + grp * 8);
            const float4 a1 = *(const float4*)(Qga + c * 32 + grp * 8 + 4);
            qfa[c][0] = (bf16)(a0.x * QSCALE); qfa[c][1] = (bf16)(a0.y * QSCALE);
            qfa[c][2] = (bf16)(a0.z * QSCALE); qfa[c][3] = (bf16)(a0.w * QSCALE);
            qfa[c][4] = (bf16)(a1.x * QSCALE); qfa[c][5] = (bf16)(a1.y * QSCALE);
            qfa[c][6] = (bf16)(a1.z * QSCALE); qfa[c][7] = (bf16)(a1.w * QSCALE);
            const float4 b0 = *(const float4*)(Qgb + c * 32 + grp * 8);
            const float4 b1 = *(const float4*)(Qgb + c * 32 + grp * 8 + 4);
            qfb[c][0] = (bf16)(b0.x * QSCALE); qfb[c][1] = (bf16)(b0.y * QSCALE);
            qfb[c][2] = (bf16)(b0.z * QSCALE); qfb[c][3] = (bf16)(b0.w * QSCALE);
            qfb[c][4] = (bf16)(b1.x * QSCALE); qfb[c][5] = (bf16)(b1.y * QSCALE);
            qfb[c][6] = (bf16)(b1.z * QSCALE); qfb[c][7] = (bf16)(b1.w * QSCALE);
        }
    }

    f32x4 oaccA[4], oaccB[4];
#pragma unroll
    for (int i = 0; i < 4; ++i) {
        oaccA[i] = (f32x4){0.f, 0.f, 0.f, 0.f};
        oaccB[i] = (f32x4){0.f, 0.f, 0.f, 0.f};
    }
    float dsumA = 0.f, dsumB = 0.f;  // per-lane denominators (q-row = col of each subtile)

    const u64* Wa = W + ((long)b * S_ + qa + col) * (S_ / 64);
    const u64* Wb = Wa + 16 * (S_ / 64);
    const unsigned short* Kbh = Kp + (long)(b * H_ + h) * S_ * D_;
    const unsigned short* Vbh = Vp + (long)(b * H_ + h) * D_ * S_;

    // gload addressing: 256 threads x 2 chunks cover 64 rows x 128 B.
    // linear LDS dest (wave-uniform base + lane*16B), inverse-swizzled global src.
    const int rl = ln >> 3;
    const int c8 = (ln & 7) ^ rl;  // (row & 7) == rl for all i, wv

    auto STAGE_ISSUE = [&](int kv0, int buf) {  // 4 gload_lds/thread
#pragma unroll
        for (int i = 0; i < 2; ++i) {
            const int row = i * 32 + wv * 8 + rl;
            gload16(Kbh + (long)(kv0 + row) * D_ + c8 * 8,
                    Ks2 + buf * TILE_E + i * 2048 + wv * 512);
            gload16(Vbh + (long)row * S_ + kv0 + c8 * 8,
                    Vt2 + buf * TILE_E + i * 2048 + wv * 512);
        }
    };

    auto STEP = [&](u64 mwa, u64 mwb, const unsigned short* Kc, const unsigned short* Vc) {
        // mask bias as MFMA C-in: 0 or -1e9
        f32x4 sa[4], sb[4];
        {
            const u64 ma = mwa >> (grp * 4), mb = mwb >> (grp * 4);
            const unsigned alo = (unsigned)ma, ahi = (unsigned)(ma >> 32);
            const unsigned blo = (unsigned)mb, bhi = (unsigned)(mb >> 32);
#pragma unroll
            for (int blk = 0; blk < 4; ++blk) {
                const unsigned wa32 = (blk < 2) ? alo : ahi;
                const unsigned wb32 = (blk < 2) ? blo : bhi;
#pragma unroll
                for (int r = 0; r < 4; ++r) {
                    const int bit = (blk & 1) * 16 + r;  // compile-time
                    sa[blk][r] = ((wa32 >> bit) & 1u) ? 0.0f : -1e9f;
                    sb[blk][r] = ((wb32 >> bit) & 1u) ? 0.0f : -1e9f;
                }
            }
        }
        // QK^T swapped; K-frags read ONCE, used by both subtiles
        __builtin_amdgcn_s_setprio(1);
#pragma unroll
        for (int blk = 0; blk < 4; ++blk) {
            const int row = blk * 16 + col;
            const int byte0 = (row * 128 + grp * 16) ^ ((row & 7) << 4);
            const int byte1 = (row * 128 + 64 + grp * 16) ^ ((row & 7) << 4);
            const bf16x8 kf0 = *(const bf16x8*)((const char*)Kc + byte0);
            const bf16x8 kf1 = *(const bf16x8*)((const char*)Kc + byte1);
            sa[blk] = __builtin_amdgcn_mfma_f32_16x16x32_bf16(kf0, qfa[0], sa[blk], 0, 0, 0);
            sa[blk] = __builtin_amdgcn_mfma_f32_16x16x32_bf16(kf1, qfa[1], sa[blk], 0, 0, 0);
            sb[blk] = __builtin_amdgcn_mfma_f32_16x16x32_bf16(kf0, qfb[0], sb[blk], 0, 0, 0);
            sb[blk] = __builtin_amdgcn_mfma_f32_16x16x32_bf16(kf1, qfb[1], sb[blk], 0, 0, 0);
        }
        __builtin_amdgcn_s_setprio(0);
        // exp2 + dsum + bf16 pack (no max subtraction; masked -> 0)
        bf16x8 pa[2], pb[2];
#pragma unroll
        for (int c = 0; c < 2; ++c)
#pragma unroll
            for (int j = 0; j < 8; ++j) {
                const int blk = 2 * c + (j >> 2), r = j & 3;
                const float ea = EXP2(sa[blk][r]);
                const float eb = EXP2(sb[blk][r]);
                dsumA += ea;
                dsumB += eb;
                pa[c][j] = (bf16)ea;
                pb[c][j] = (bf16)eb;
            }
        // PV; V-frags read ONCE, used by both subtiles
        __builtin_amdgcn_s_setprio(1);
#pragma unroll
        for (int c = 0; c < 2; ++c)
#pragma unroll
            for (int db = 0; db < 4; ++db) {
                const int vrow = db * 16 + col;
                const int byte = (vrow * 128 + c * 64 + grp * 16) ^ ((vrow & 7) << 4);
                const bf16x8 vf = *(const bf16x8*)((const char*)Vc + byte);
                oaccA[db] = __builtin_amdgcn_mfma_f32_16x16x32_bf16(pa[c], vf, oaccA[db], 0, 0, 0);
                oaccB[db] = __builtin_amdgcn_mfma_f32_16x16x32_bf16(pb[c], vf, oaccB[db], 0, 0, 0);
            }
        __builtin_amdgcn_s_setprio(0);
    };

#define WAIT0_BAR() do { asm volatile("s_waitcnt vmcnt(0)" ::: "memory"); \
    __builtin_amdgcn_s_barrier(); __builtin_amdgcn_sched_barrier(0); } while (0)

    // prologue: stage tile 0
    STAGE_ISSUE(0, 0);
    WAIT0_BAR();

#pragma unroll 1
    for (int t = 0; t < NT; t += 2) {  // NT = 32 even; slots compile-time
        {
            const u64 mwa = Wa[t], mwb = Wb[t];
            if (t + 1 < NT) STAGE_ISSUE((t + 1) * KT, 1);
            STEP(mwa, mwb, Ks2, Vt2);
            WAIT0_BAR();
        }
        {
            const u64 mwa = Wa[t + 1], mwb = Wb[t + 1];
            if (t + 2 < NT) STAGE_ISSUE((t + 2) * KT, 0);
            STEP(mwa, mwb, Ks2 + TILE_E, Vt2 + TILE_E);
            WAIT0_BAR();
        }
    }

    // epilogue: reduce dsum across the 4 lane-replicas, broadcast per output row
    dsumA += __shfl_xor(dsumA, 16);
    dsumA += __shfl_xor(dsumA, 32);
    dsumB += __shfl_xor(dsumB, 16);
    dsumB += __shfl_xor(dsumB, 32);
    float* Oa = O + ((long)((b * H_ + h) * S_) + qa) * D_;
#pragma unroll
    for (int r = 0; r < 4; ++r) {
        const float ia = 1.0f / __shfl(dsumA, grp * 20 + r);  // lane with col == grp*4+r
        const float ib = 1.0f / __shfl(dsumB, grp * 20 + r);
#pragma unroll
        for (int db = 0; db < 4; ++db) {
            Oa[(grp * 4 + r) * D_ + db * 16 + col] = oaccA[db][r] * ia;
            Oa[(16 + grp * 4 + r) * D_ + db * 16 + col] = oaccB[db][r] * ib;
        }
    }
#undef WAIT0_BAR
}

// ---- fallback kernel (512 thr, 16 q/wave, reg-staging, __syncthreads) ----
template <int MODE>
__global__ __launch_bounds__(512, 4) void attn_fb(
    const float* __restrict__ Q, const float* __restrict__ K,
    const float* __restrict__ V, const int* __restrict__ M,
    const u64* __restrict__ W, float* __restrict__ O)
{
    __shared__ __attribute__((aligned(16))) unsigned short Ks2[2 * TILE_E];
    __shared__ __attribute__((aligned(16))) unsigned short Vt2[2 * TILE_E];

    const int tid = threadIdx.x;
    const int wv = tid >> 6, ln = tid & 63;
    const int col = ln & 15, grp = ln >> 4;

    int bid = blockIdx.x;
    bid = (bid & 7) * 128 + (bid >> 3);
    const int qt = bid & 15;
    const int h = (bid >> 4) & 7;
    const int b = bid >> 7;
    const int qw = qt * 128 + wv * 16;

    const float* Qg = Q + ((long)((b * H_ + h) * S_) + qw + col) * D_;
    bf16x8 qf[2];
#pragma unroll
    for (int c = 0; c < 2; ++c) {
        const float4 a0 = *(const float4*)(Qg + c * 32 + grp * 8);
        const float4 a1 = *(const float4*)(Qg + c * 32 + grp * 8 + 4);
        qf[c][0] = (bf16)(a0.x * QSCALE); qf[c][1] = (bf16)(a0.y * QSCALE);
        qf[c][2] = (bf16)(a0.z * QSCALE); qf[c][3] = (bf16)(a0.w * QSCALE);
        qf[c][4] = (bf16)(a1.x * QSCALE); qf[c][5] = (bf16)(a1.y * QSCALE);
        qf[c][6] = (bf16)(a1.z * QSCALE); qf[c][7] = (bf16)(a1.w * QSCALE);
    }
    bf16x8 onesf;
#pragma unroll
    for (int j = 0; j < 8; ++j) onesf[j] = (bf16)1.0f;

    f32x4 oacc[4];
#pragma unroll
    for (int i = 0; i < 4; ++i) oacc[i] = (f32x4){0.f, 0.f, 0.f, 0.f};
    f32x4 accs = (f32x4){0.f, 0.f, 0.f, 0.f};

    const u64* Wg = (MODE >= 1) ? (W + ((long)b * S_ + qw + col) * (S_ / 64)) : nullptr;
    const int* Mg = (MODE == 0) ? (M + ((long)b * S_ + qw + col) * S_) : nullptr;
    const float* Kf = K + (long)(b * H_ + h) * S_ * D_;
    const float* Vf = V + (long)(b * H_ + h) * S_ * D_;

    float4 ka[2];
    float va[8];
    const int vd = ln, kg0 = wv;

    auto LOADT = [&](int kv0) {
#pragma unroll
        for (int i = 0; i < 2; ++i) {
            const int idx4 = i * 512 + tid;
            const int row = idx4 >> 4, c4 = idx4 & 15;
            ka[i] = *(const float4*)(Kf + (long)(kv0 + row) * D_ + c4 * 4);
        }
#pragma unroll
        for (int i = 0; i < 2; ++i) {
            const int kg = kg0 + i * 8;
            const int kvn = phi_inv(kg * 4);
#pragma unroll
            for (int j = 0; j < 4; ++j)
                va[i * 4 + j] = Vf[(long)(kv0 + kvn + j) * D_ + vd];
        }
    };
    auto WRITET = [&](int buf) {
#pragma unroll
        for (int i = 0; i < 2; ++i) {
            const int idx4 = i * 512 + tid;
            const int row = idx4 >> 4, c4 = idx4 & 15;
            const int byte = (row * 128 + c4 * 8) ^ ((row & 7) << 4);
            ushort4 w;
            w.x = bfb(ka[i].x); w.y = bfb(ka[i].y);
            w.z = bfb(ka[i].z); w.w = bfb(ka[i].w);
            *(ushort4*)((char*)(Ks2 + buf * TILE_E) + byte) = w;
        }
#pragma unroll
        for (int i = 0; i < 2; ++i) {
            const int kg = kg0 + i * 8;
            const int byte = (vd * 128 + kg * 8) ^ ((vd & 7) << 4);
            ushort4 w;
            w.x = bfb(va[i * 4 + 0]); w.y = bfb(va[i * 4 + 1]);
            w.z = bfb(va[i * 4 + 2]); w.w = bfb(va[i * 4 + 3]);
            *(ushort4*)((char*)(Vt2 + buf * TILE_E) + byte) = w;
        }
    };
    auto FSTEP = [&](u64 mwfull, int t, const unsigned short* Kc, const unsigned short* Vc) {
        f32x4 sc[4];
        const f32x4 zq = (f32x4){0.f, 0.f, 0.f, 0.f};
#pragma unroll
        for (int blk = 0; blk < 4; ++blk) {
            const int row = blk * 16 + col;
            const int byte0 = (row * 128 + grp * 16) ^ ((row & 7) << 4);
            const int byte1 = (row * 128 + 64 + grp * 16) ^ ((row & 7) << 4);
            const bf16x8 kf0 = *(const bf16x8*)((const char*)Kc + byte0);
            const bf16x8 kf1 = *(const bf16x8*)((const char*)Kc + byte1);
            sc[blk] = __builtin_amdgcn_mfma_f32_16x16x32_bf16(kf0, qf[0], zq, 0, 0, 0);
            sc[blk] = __builtin_amdgcn_mfma_f32_16x16x32_bf16(kf1, qf[1], sc[blk], 0, 0, 0);
        }
        bf16x8 pf[2];
        if (MODE >= 1) {
            const u64 mws = mwfull >> (grp * 4);
            const unsigned mlo = (unsigned)mws, mhi = (unsigned)(mws >> 32);
#pragma unroll
            for (int c = 0; c < 2; ++c)
#pragma unroll
                for (int j = 0; j < 8; ++j) {
                    const int blk = 2 * c + (j >> 2), r = j & 3;
                    const unsigned w32 = (blk < 2) ? mlo : mhi;
                    const int bit = (blk & 1) * 16 + r;
                    const float s = ((w32 >> bit) & 1u) ? sc[blk][r] : -1e9f;
                    pf[c][j] = (bf16)EXP2(s);
                }
        } else {
#pragma unroll
            for (int c = 0; c < 2; ++c)
#pragma unroll
                for (int j = 0; j < 8; ++j) {
                    const int blk = 2 * c + (j >> 2), r = j & 3;
                    const int mv = Mg[t * KT + blk * 16 + grp * 4 + r];
                    const float s = mv ? sc[blk][r] : -1e9f;
                    pf[c][j] = (bf16)EXP2(s);
                }
        }
        accs = __builtin_amdgcn_mfma_f32_16x16x32_bf16(pf[0], onesf, accs, 0, 0, 0);
        accs = __builtin_amdgcn_mfma_f32_16x16x32_bf16(pf[1], onesf, accs, 0, 0, 0);
#pragma unroll
        for (int c = 0; c < 2; ++c)
#pragma unroll
            for (int db = 0; db < 4; ++db) {
                const int vrow = db * 16 + col;
                const int byte = (vrow * 128 + c * 64 + grp * 16) ^ ((vrow & 7) << 4);
                const bf16x8 vf = *(const bf16x8*)((const char*)Vc + byte);
                oacc[db] = __builtin_amdgcn_mfma_f32_16x16x32_bf16(pf[c], vf, oacc[db], 0, 0, 0);
            }
    };

    LOADT(0);
    WRITET(0);
    __syncthreads();
#pragma unroll 1
    for (int t = 0; t < NT; t += 2) {
        if (t + 1 < NT) LOADT((t + 1) * KT);
        FSTEP(MODE >= 1 ? Wg[t] : 0ull, t, Ks2, Vt2);
        if (t + 1 < NT) WRITET(1);
        __syncthreads();
        if (t + 2 < NT) LOADT((t + 2) * KT);
        FSTEP(MODE >= 1 ? Wg[t + 1] : 0ull, t + 1, Ks2 + TILE_E, Vt2 + TILE_E);
        if (t + 2 < NT) WRITET(0);
        __syncthreads();
    }

    float* Og = O + ((long)((b * H_ + h) * S_) + qw) * D_;
#pragma unroll
    for (int r = 0; r < 4; ++r) {
        const float inv = 1.0f / accs[r];
#pragma unroll
        for (int db = 0; db < 4; ++db)
            Og[(grp * 4 + r) * D_ + db * 16 + col] = oacc[db][r] * inv;
    }
}

extern "C" void kernel_launch(void* const* d_in, const int* in_sizes, int n_in,
                              void* d_out, int out_size, void* d_ws, size_t ws_size,
                              hipStream_t stream) {
    (void)in_sizes; (void)n_in; (void)out_size;
    const float* Q = (const float*)d_in[0];
    const float* K = (const float*)d_in[1];
    const float* V = (const float*)d_in[2];
    const int*   M = (const int*)d_in[3];
    float* O = (float*)d_out;

    const size_t szW = (size_t)B_ * S_ * (S_ / 64) * sizeof(u64);      // 4 MB
    const size_t szK = (size_t)B_ * H_ * S_ * D_ * 2;                  // 16 MB
    const int nmaskblk = (B_ * S_ * (S_ / 64)) / 32;                   // 16384

    if (ws_size >= szW + 2 * szK) {
        u64* W = (u64*)d_ws;
        unsigned short* Kp = (unsigned short*)((char*)d_ws + szW);
        unsigned short* Vp = (unsigned short*)((char*)d_ws + szW + szK);
        prep_fused<<<KV_BLOCKS + nmaskblk, 256, 0, stream>>>(K, V, Kp, Vp, M, W);
        attn_main<<<B_ * H_ * (S_ / QT), 256, 0, stream>>>(Q, W, Kp, Vp, O);  // 1024 blocks
    } else if (ws_size >= szW) {
        u64* W = (u64*)d_ws;
        prep_fused<<<KV_BLOCKS + nmaskblk, 256, 0, stream>>>(K, V, nullptr, nullptr, M, W);
        attn_fb<1><<<1024, 512, 0, stream>>>(Q, K, V, M, W, O);
    } else {
        attn_fb<0><<<1024, 512, 0, stream>>>(Q, K, V, M, nullptr, O);
    }
}

// Round 13
// 162.863 us; speedup vs baseline: 1.8573x; 1.2010x over previous
//
#include <hip/hip_runtime.h>
#include <hip/hip_bf16.h>
#include <stdint.h>

// SelfAttention B=8 H=8 S=2048 D=64 fp32, mask[B,S,S] int32 (0 -> -1e9).
// Round 13: independent-barrier-groups test WITHOUT spill. 256-thr blocks
// (4 waves x 16 q, QT=64), single subtile (regs ~78 < 128 cap), 32 KB LDS
// (2 slots) -> 4-5 blocks/CU co-resident = 16-20 waves/CU in 4-5 independent
// groups (vs R9's 2). Grid 2048. Keeps: max-free exp2 softmax, mask bias as
// MFMA C-in, ones-column denominator, K/V bf16 + mask bitpack prepass,
// gload_lds staging, setprio, XCD swizzle, stage-ahead-1 + vmcnt(0) barriers.

#define B_ 8
#define H_ 8
#define S_ 2048
#define D_ 64
#define QT 64   // q rows per block: 4 waves x 16
#define KT 64
#define NT (S_ / KT)
#define TILE_E (KT * D_)  // 4096 shorts = 8 KB per K (or V) slot
#define LOG2E 1.44269504088896340736f
#define QSCALE (0.125f * LOG2E)

typedef __bf16 bf16;
typedef bf16 bf16x8 __attribute__((ext_vector_type(8)));
typedef float f32x4 __attribute__((ext_vector_type(4)));
typedef unsigned short ushort8_t __attribute__((ext_vector_type(8)));
typedef unsigned long long u64;

#if __has_builtin(__builtin_amdgcn_exp2f)
#define EXP2(x) __builtin_amdgcn_exp2f(x)
#else
#define EXP2(x) exp2f(x)
#endif

static __device__ __forceinline__ unsigned short bfb(float f) {
    bf16 h = (bf16)f;  // RNE
    return __builtin_bit_cast(unsigned short, h);
}
// kv' bit-permutation: kv bits [b5 b4 b3 b2 b1 b0] -> kv' = [b5 b3 b2 b4 b1 b0].
static __device__ __forceinline__ int phi_inv(int c) {
    return ((c >> 5) & 1) * 32 + ((c >> 2) & 1) * 16 + ((c >> 4) & 1) * 8 +
           ((c >> 3) & 1) * 4 + (c & 3);
}
static __device__ __forceinline__ void gload16(const unsigned short* g, unsigned short* l) {
    __builtin_amdgcn_global_load_lds(
        (const __attribute__((address_space(1))) unsigned int*)g,
        (__attribute__((address_space(3))) unsigned int*)l, 16, 0, 0);
}

#define KV_BLOCKS (B_ * H_ * NT)  // 2048

// Fused prepass: blocks [0, KV_BLOCKS) convert K/V (if Ko != null); rest bitpack mask.
__global__ __launch_bounds__(256) void prep_fused(
    const float* __restrict__ K, const float* __restrict__ V,
    unsigned short* __restrict__ Ko, unsigned short* __restrict__ Vo,
    const int* __restrict__ M, u64* __restrict__ W) {
    const int tid = threadIdx.x;
    if (blockIdx.x >= KV_BLOCKS) {
        const int ln = tid & 63;
        const int w0 = (blockIdx.x - KV_BLOCKS) * 32 + (tid >> 6) * 8;
#pragma unroll
        for (int j = 0; j < 8; ++j) {
            const int v = M[(long)(w0 + j) * 64 + ln];
            const u64 bal = __ballot(v != 0);
            if (ln == 0) W[w0 + j] = bal;
        }
        return;
    }
    if (Ko == nullptr) return;
    __shared__ float Vl[64][65];
    const int t = blockIdx.x & (NT - 1);
    const int bh = blockIdx.x >> 5;
    const float* Kg = K + ((long)bh * S_ + t * 64) * D_;
    const float* Vg = V + ((long)bh * S_ + t * 64) * D_;
    unsigned short* Kout = Ko + ((long)bh * S_ + t * 64) * D_;
    unsigned short* Vout = Vo + (long)bh * D_ * S_ + t * 64;
    {   // K convert: 16 elems/thread
        const int kv = tid >> 2, d0 = (tid & 3) * 16;
#pragma unroll
        for (int half = 0; half < 2; ++half) {
            const float4 f0 = *(const float4*)(Kg + kv * D_ + d0 + half * 8);
            const float4 f1 = *(const float4*)(Kg + kv * D_ + d0 + half * 8 + 4);
            ushort8_t u;
            u[0] = bfb(f0.x); u[1] = bfb(f0.y); u[2] = bfb(f0.z); u[3] = bfb(f0.w);
            u[4] = bfb(f1.x); u[5] = bfb(f1.y); u[6] = bfb(f1.z); u[7] = bfb(f1.w);
            *(ushort8_t*)(Kout + kv * D_ + d0 + half * 8) = u;
        }
    }
    {   // V stage to LDS (coalesced reads)
#pragma unroll
        for (int i = 0; i < 4; ++i) {
            const int kv = i * 16 + (tid >> 4);
            const int d4 = (tid & 15) * 4;
            const float4 f = *(const float4*)(Vg + kv * D_ + d4);
            Vl[kv][d4 + 0] = f.x; Vl[kv][d4 + 1] = f.y;
            Vl[kv][d4 + 2] = f.z; Vl[kv][d4 + 3] = f.w;
        }
    }
    __syncthreads();
    {   // write transposed+permuted, coalesced ushort4 stores
#pragma unroll
        for (int j = 0; j < 4; ++j) {
            const int chunk = j * 256 + tid;
            const int d = chunk >> 4, q4 = chunk & 15;
            ushort4 w;
            w.x = bfb(Vl[phi_inv(q4 * 4 + 0)][d]);
            w.y = bfb(Vl[phi_inv(q4 * 4 + 1)][d]);
            w.z = bfb(Vl[phi_inv(q4 * 4 + 2)][d]);
            w.w = bfb(Vl[phi_inv(q4 * 4 + 3)][d]);
            *(ushort4*)(Vout + (long)d * S_ + q4 * 4) = w;
        }
    }
}

// ---- main: 4 waves x 16 q-rows, 32 KB LDS, regs ~78 -> 4-5 blocks/CU ----
__global__ __launch_bounds__(256, 4) void attn_main(
    const float* __restrict__ Q, const u64* __restrict__ W,
    const unsigned short* __restrict__ Kp, const unsigned short* __restrict__ Vp,
    float* __restrict__ O)
{
    __shared__ __attribute__((aligned(16))) unsigned short Ks2[2 * TILE_E];  // 16 KB
    __shared__ __attribute__((aligned(16))) unsigned short Vt2[2 * TILE_E];  // 16 KB

    const int tid = threadIdx.x;
    const int wv = tid >> 6, ln = tid & 63;
    const int col = ln & 15, grp = ln >> 4;

    int bid = blockIdx.x;
    bid = (bid & 7) * 256 + (bid >> 3);  // XCD chunk swizzle (2048 % 8 == 0, bijective)
    const int qt = bid & 31;             // 32 q-tiles of 64 rows
    const int h = (bid >> 5) & 7;
    const int b = bid >> 8;
    const int qw = qt * QT + wv * 16;

    // Q frag (B-operand): lane holds Q[q=col][d = c*32+grp*8+j] * QSCALE
    const float* Qg = Q + ((long)((b * H_ + h) * S_) + qw + col) * D_;
    bf16x8 qf[2];
#pragma unroll
    for (int c = 0; c < 2; ++c) {
        const float4 a0 = *(const float4*)(Qg + c * 32 + grp * 8);
        const float4 a1 = *(const float4*)(Qg + c * 32 + grp * 8 + 4);
        qf[c][0] = (bf16)(a0.x * QSCALE); qf[c][1] = (bf16)(a0.y * QSCALE);
        qf[c][2] = (bf16)(a0.z * QSCALE); qf[c][3] = (bf16)(a0.w * QSCALE);
        qf[c][4] = (bf16)(a1.x * QSCALE); qf[c][5] = (bf16)(a1.y * QSCALE);
        qf[c][6] = (bf16)(a1.z * QSCALE); qf[c][7] = (bf16)(a1.w * QSCALE);
    }
    bf16x8 onesf;
#pragma unroll
    for (int j = 0; j < 8; ++j) onesf[j] = (bf16)1.0f;

    f32x4 oacc[4];
#pragma unroll
    for (int i = 0; i < 4; ++i) oacc[i] = (f32x4){0.f, 0.f, 0.f, 0.f};
    f32x4 accs = (f32x4){0.f, 0.f, 0.f, 0.f};  // accs[r] = denominator for q=grp*4+r

    const u64* Wg = W + ((long)b * S_ + qw + col) * (S_ / 64);
    const unsigned short* Kbh = Kp + (long)(b * H_ + h) * S_ * D_;
    const unsigned short* Vbh = Vp + (long)(b * H_ + h) * D_ * S_;

    // gload addressing: 256 threads x 2 chunks cover 64 rows x 128 B.
    // linear LDS dest, inverse-swizzled global source.
    const int rl = ln >> 3;
    const int c8 = (ln & 7) ^ rl;  // (row & 7) == rl for all chunks

    auto STAGE_ISSUE = [&](int kv0, int buf) {  // 4 gload_lds/thread
#pragma unroll
        for (int i = 0; i < 2; ++i) {
            const int row = i * 32 + wv * 8 + rl;
            gload16(Kbh + (long)(kv0 + row) * D_ + c8 * 8,
                    Ks2 + buf * TILE_E + i * 2048 + wv * 512);
            gload16(Vbh + (long)row * S_ + kv0 + c8 * 8,
                    Vt2 + buf * TILE_E + i * 2048 + wv * 512);
        }
    };

    auto STEP = [&](u64 mwfull, const unsigned short* Kc, const unsigned short* Vc) {
        // mask bias as MFMA C-in: 0 or -1e9
        f32x4 sc[4];
        {
            const u64 mws = mwfull >> (grp * 4);
            const unsigned mlo = (unsigned)mws, mhi = (unsigned)(mws >> 32);
#pragma unroll
            for (int blk = 0; blk < 4; ++blk) {
                const unsigned w32 = (blk < 2) ? mlo : mhi;
#pragma unroll
                for (int r = 0; r < 4; ++r) {
                    const int bit = (blk & 1) * 16 + r;  // compile-time
                    sc[blk][r] = ((w32 >> bit) & 1u) ? 0.0f : -1e9f;
                }
            }
        }
        // QK^T swapped (log2 domain): lane holds q=col, kv = blk*16 + grp*4 + r
        __builtin_amdgcn_s_setprio(1);
#pragma unroll
        for (int blk = 0; blk < 4; ++blk) {
            const int row = blk * 16 + col;
            const int byte0 = (row * 128 + grp * 16) ^ ((row & 7) << 4);
            const int byte1 = (row * 128 + 64 + grp * 16) ^ ((row & 7) << 4);
            const bf16x8 kf0 = *(const bf16x8*)((const char*)Kc + byte0);
            const bf16x8 kf1 = *(const bf16x8*)((const char*)Kc + byte1);
            sc[blk] = __builtin_amdgcn_mfma_f32_16x16x32_bf16(kf0, qf[0], sc[blk], 0, 0, 0);
            sc[blk] = __builtin_amdgcn_mfma_f32_16x16x32_bf16(kf1, qf[1], sc[blk], 0, 0, 0);
        }
        __builtin_amdgcn_s_setprio(0);
        // exp2 + bf16 pack (no max subtraction; masked -> exp2(-1e9) = 0)
        bf16x8 pf[2];
#pragma unroll
        for (int c = 0; c < 2; ++c)
#pragma unroll
            for (int j = 0; j < 8; ++j)
                pf[c][j] = (bf16)EXP2(sc[2 * c + (j >> 2)][j & 3]);
        // denominator + PV via MFMA
        __builtin_amdgcn_s_setprio(1);
        accs = __builtin_amdgcn_mfma_f32_16x16x32_bf16(pf[0], onesf, accs, 0, 0, 0);
        accs = __builtin_amdgcn_mfma_f32_16x16x32_bf16(pf[1], onesf, accs, 0, 0, 0);
#pragma unroll
        for (int c = 0; c < 2; ++c)
#pragma unroll
            for (int db = 0; db < 4; ++db) {
                const int vrow = db * 16 + col;
                const int byte = (vrow * 128 + c * 64 + grp * 16) ^ ((vrow & 7) << 4);
                const bf16x8 vf = *(const bf16x8*)((const char*)Vc + byte);
                oacc[db] = __builtin_amdgcn_mfma_f32_16x16x32_bf16(pf[c], vf, oacc[db], 0, 0, 0);
            }
        __builtin_amdgcn_s_setprio(0);
    };

#define WAIT0_BAR() do { asm volatile("s_waitcnt vmcnt(0)" ::: "memory"); \
    __builtin_amdgcn_s_barrier(); __builtin_amdgcn_sched_barrier(0); } while (0)

    // prologue: stage tile 0
    STAGE_ISSUE(0, 0);
    WAIT0_BAR();

#pragma unroll 1
    for (int t = 0; t < NT; t += 2) {  // NT = 32 even; slots compile-time
        {
            const u64 mw = Wg[t];
            if (t + 1 < NT) STAGE_ISSUE((t + 1) * KT, 1);
            STEP(mw, Ks2, Vt2);
            WAIT0_BAR();
        }
        {
            const u64 mw = Wg[t + 1];
            if (t + 2 < NT) STAGE_ISSUE((t + 2) * KT, 0);
            STEP(mw, Ks2 + TILE_E, Vt2 + TILE_E);
            WAIT0_BAR();
        }
    }

    // epilogue: accs[r] is the denominator, same layout as oacc — no shuffles
    float* Og = O + ((long)((b * H_ + h) * S_) + qw) * D_;
#pragma unroll
    for (int r = 0; r < 4; ++r) {
        const float inv = 1.0f / accs[r];
#pragma unroll
        for (int db = 0; db < 4; ++db)
            Og[(grp * 4 + r) * D_ + db * 16 + col] = oacc[db][r] * inv;
    }
#undef WAIT0_BAR
}

// ---- fallback kernel (512 thr, 16 q/wave, reg-staging, __syncthreads) ----
template <int MODE>
__global__ __launch_bounds__(512, 4) void attn_fb(
    const float* __restrict__ Q, const float* __restrict__ K,
    const float* __restrict__ V, const int* __restrict__ M,
    const u64* __restrict__ W, float* __restrict__ O)
{
    __shared__ __attribute__((aligned(16))) unsigned short Ks2[2 * TILE_E];
    __shared__ __attribute__((aligned(16))) unsigned short Vt2[2 * TILE_E];

    const int tid = threadIdx.x;
    const int wv = tid >> 6, ln = tid & 63;
    const int col = ln & 15, grp = ln >> 4;

    int bid = blockIdx.x;
    bid = (bid & 7) * 128 + (bid >> 3);
    const int qt = bid & 15;
    const int h = (bid >> 4) & 7;
    const int b = bid >> 7;
    const int qw = qt * 128 + wv * 16;

    const float* Qg = Q + ((long)((b * H_ + h) * S_) + qw + col) * D_;
    bf16x8 qf[2];
#pragma unroll
    for (int c = 0; c < 2; ++c) {
        const float4 a0 = *(const float4*)(Qg + c * 32 + grp * 8);
        const float4 a1 = *(const float4*)(Qg + c * 32 + grp * 8 + 4);
        qf[c][0] = (bf16)(a0.x * QSCALE); qf[c][1] = (bf16)(a0.y * QSCALE);
        qf[c][2] = (bf16)(a0.z * QSCALE); qf[c][3] = (bf16)(a0.w * QSCALE);
        qf[c][4] = (bf16)(a1.x * QSCALE); qf[c][5] = (bf16)(a1.y * QSCALE);
        qf[c][6] = (bf16)(a1.z * QSCALE); qf[c][7] = (bf16)(a1.w * QSCALE);
    }
    bf16x8 onesf;
#pragma unroll
    for (int j = 0; j < 8; ++j) onesf[j] = (bf16)1.0f;

    f32x4 oacc[4];
#pragma unroll
    for (int i = 0; i < 4; ++i) oacc[i] = (f32x4){0.f, 0.f, 0.f, 0.f};
    f32x4 accs = (f32x4){0.f, 0.f, 0.f, 0.f};

    const u64* Wg = (MODE >= 1) ? (W + ((long)b * S_ + qw + col) * (S_ / 64)) : nullptr;
    const int* Mg = (MODE == 0) ? (M + ((long)b * S_ + qw + col) * S_) : nullptr;
    const float* Kf = K + (long)(b * H_ + h) * S_ * D_;
    const float* Vf = V + (long)(b * H_ + h) * S_ * D_;

    float4 ka[2];
    float va[8];
    const int vd = ln, kg0 = wv;

    auto LOADT = [&](int kv0) {
#pragma unroll
        for (int i = 0; i < 2; ++i) {
            const int idx4 = i * 512 + tid;
            const int row = idx4 >> 4, c4 = idx4 & 15;
            ka[i] = *(const float4*)(Kf + (long)(kv0 + row) * D_ + c4 * 4);
        }
#pragma unroll
        for (int i = 0; i < 2; ++i) {
            const int kg = kg0 + i * 8;
            const int kvn = phi_inv(kg * 4);
#pragma unroll
            for (int j = 0; j < 4; ++j)
                va[i * 4 + j] = Vf[(long)(kv0 + kvn + j) * D_ + vd];
        }
    };
    auto WRITET = [&](int buf) {
#pragma unroll
        for (int i = 0; i < 2; ++i) {
            const int idx4 = i * 512 + tid;
            const int row = idx4 >> 4, c4 = idx4 & 15;
            const int byte = (row * 128 + c4 * 8) ^ ((row & 7) << 4);
            ushort4 w;
            w.x = bfb(ka[i].x); w.y = bfb(ka[i].y);
            w.z = bfb(ka[i].z); w.w = bfb(ka[i].w);
            *(ushort4*)((char*)(Ks2 + buf * TILE_E) + byte) = w;
        }
#pragma unroll
        for (int i = 0; i < 2; ++i) {
            const int kg = kg0 + i * 8;
            const int byte = (vd * 128 + kg * 8) ^ ((vd & 7) << 4);
            ushort4 w;
            w.x = bfb(va[i * 4 + 0]); w.y = bfb(va[i * 4 + 1]);
            w.z = bfb(va[i * 4 + 2]); w.w = bfb(va[i * 4 + 3]);
            *(ushort4*)((char*)(Vt2 + buf * TILE_E) + byte) = w;
        }
    };
    auto FSTEP = [&](u64 mwfull, int t, const unsigned short* Kc, const unsigned short* Vc) {
        f32x4 sc[4];
        const f32x4 zq = (f32x4){0.f, 0.f, 0.f, 0.f};
#pragma unroll
        for (int blk = 0; blk < 4; ++blk) {
            const int row = blk * 16 + col;
            const int byte0 = (row * 128 + grp * 16) ^ ((row & 7) << 4);
            const int byte1 = (row * 128 + 64 + grp * 16) ^ ((row & 7) << 4);
            const bf16x8 kf0 = *(const bf16x8*)((const char*)Kc + byte0);
            const bf16x8 kf1 = *(const bf16x8*)((const char*)Kc + byte1);
            sc[blk] = __builtin_amdgcn_mfma_f32_16x16x32_bf16(kf0, qf[0], zq, 0, 0, 0);
            sc[blk] = __builtin_amdgcn_mfma_f32_16x16x32_bf16(kf1, qf[1], sc[blk], 0, 0, 0);
        }
        bf16x8 pf[2];
        if (MODE >= 1) {
            const u64 mws = mwfull >> (grp * 4);
            const unsigned mlo = (unsigned)mws, mhi = (unsigned)(mws >> 32);
#pragma unroll
            for (int c = 0; c < 2; ++c)
#pragma unroll
                for (int j = 0; j < 8; ++j) {
                    const int blk = 2 * c + (j >> 2), r = j & 3;
                    const unsigned w32 = (blk < 2) ? mlo : mhi;
                    const int bit = (blk & 1) * 16 + r;
                    const float s = ((w32 >> bit) & 1u) ? sc[blk][r] : -1e9f;
                    pf[c][j] = (bf16)EXP2(s);
                }
        } else {
#pragma unroll
            for (int c = 0; c < 2; ++c)
#pragma unroll
                for (int j = 0; j < 8; ++j) {
                    const int blk = 2 * c + (j >> 2), r = j & 3;
                    const int mv = Mg[t * KT + blk * 16 + grp * 4 + r];
                    const float s = mv ? sc[blk][r] : -1e9f;
                    pf[c][j] = (bf16)EXP2(s);
                }
        }
        accs = __builtin_amdgcn_mfma_f32_16x16x32_bf16(pf[0], onesf, accs, 0, 0, 0);
        accs = __builtin_amdgcn_mfma_f32_16x16x32_bf16(pf[1], onesf, accs, 0, 0, 0);
#pragma unroll
        for (int c = 0; c < 2; ++c)
#pragma unroll
            for (int db = 0; db < 4; ++db) {
                const int vrow = db * 16 + col;
                const int byte = (vrow * 128 + c * 64 + grp * 16) ^ ((vrow & 7) << 4);
                const bf16x8 vf = *(const bf16x8*)((const char*)Vc + byte);
                oacc[db] = __builtin_amdgcn_mfma_f32_16x16x32_bf16(pf[c], vf, oacc[db], 0, 0, 0);
            }
    };

    LOADT(0);
    WRITET(0);
    __syncthreads();
#pragma unroll 1
    for (int t = 0; t < NT; t += 2) {
        if (t + 1 < NT) LOADT((t + 1) * KT);
        FSTEP(MODE >= 1 ? Wg[t] : 0ull, t, Ks2, Vt2);
        if (t + 1 < NT) WRITET(1);
        __syncthreads();
        if (t + 2 < NT) LOADT((t + 2) * KT);
        FSTEP(MODE >= 1 ? Wg[t + 1] : 0ull, t + 1, Ks2 + TILE_E, Vt2 + TILE_E);
        if (t + 2 < NT) WRITET(0);
        __syncthreads();
    }

    float* Og = O + ((long)((b * H_ + h) * S_) + qw) * D_;
#pragma unroll
    for (int r = 0; r < 4; ++r) {
        const float inv = 1.0f / accs[r];
#pragma unroll
        for (int db = 0; db < 4; ++db)
            Og[(grp * 4 + r) * D_ + db * 16 + col] = oacc[db][r] * inv;
    }
}

extern "C" void kernel_launch(void* const* d_in, const int* in_sizes, int n_in,
                              void* d_out, int out_size, void* d_ws, size_t ws_size,
                              hipStream_t stream) {
    (void)in_sizes; (void)n_in; (void)out_size;
    const float* Q = (const float*)d_in[0];
    const float* K = (const float*)d_in[1];
    const float* V = (const float*)d_in[2];
    const int*   M = (const int*)d_in[3];
    float* O = (float*)d_out;

    const size_t szW = (size_t)B_ * S_ * (S_ / 64) * sizeof(u64);      // 4 MB
    const size_t szK = (size_t)B_ * H_ * S_ * D_ * 2;                  // 16 MB
    const int nmaskblk = (B_ * S_ * (S_ / 64)) / 32;                   // 16384

    if (ws_size >= szW + 2 * szK) {
        u64* W = (u64*)d_ws;
        unsigned short* Kp = (unsigned short*)((char*)d_ws + szW);
        unsigned short* Vp = (unsigned short*)((char*)d_ws + szW + szK);
        prep_fused<<<KV_BLOCKS + nmaskblk, 256, 0, stream>>>(K, V, Kp, Vp, M, W);
        attn_main<<<B_ * H_ * (S_ / QT), 256, 0, stream>>>(Q, W, Kp, Vp, O);  // 2048 blocks
    } else if (ws_size >= szW) {
        u64* W = (u64*)d_ws;
        prep_fused<<<KV_BLOCKS + nmaskblk, 256, 0, stream>>>(K, V, nullptr, nullptr, M, W);
        attn_fb<1><<<1024, 512, 0, stream>>>(Q, K, V, M, W, O);
    } else {
        attn_fb<0><<<1024, 512, 0, stream>>>(Q, K, V, M, nullptr, O);
    }
}

// Round 14
// 155.737 us; speedup vs baseline: 1.9423x; 1.0458x over previous
//
#include <hip/hip_runtime.h>
#include <hip/hip_bf16.h>
#include <stdint.h>

// SelfAttention B=8 H=8 S=2048 D=64 fp32, mask[B,S,S] int32 (0 -> -1e9).
// FINAL (revert to best-measured R6 config, 155.45 us total / 113.5 us main):
// depth-2 prefetch pipeline, 4 LDS buffer slots (t&3 compile-time), raw
// s_barrier + counted s_waitcnt vmcnt(2) so prefetch stays in flight across
// barriers; max-free exp2 softmax (scores provably bounded -> no running max);
// K/V bf16 + mask-bitpack prepass in d_ws; global_load_lds width-16 staging
// (linear LDS dest + inverse-swizzled global source + swizzled reads);
// swapped QK^T (lane-local P via kv' bit-permutation on V); ones-column
// denominator via MFMA; setprio around MFMA clusters; XCD-chunked swizzle.
// Plateau notes (R6-R13): time invariant at 112-118 us main across counted-
// vmcnt depth, loop rotation, 2x tile sharing, and block-granularity changes;
// occupancy hard-capped at 4 waves/SIMD by accumulator regs (>64 total);
// forcing <=64 spills ~1 GB (R10-R12). ~615 TF effective, ~25% dense peak.

#define B_ 8
#define H_ 8
#define S_ 2048
#define D_ 64
#define QT 128
#define KT 64
#define NT (S_ / KT)
#define TILE_E (KT * D_)  // 4096 shorts = 8 KB per buffer slot
#define LOG2E 1.44269504088896340736f
#define QSCALE (0.125f * LOG2E)

typedef __bf16 bf16;
typedef bf16 bf16x8 __attribute__((ext_vector_type(8)));
typedef float f32x4 __attribute__((ext_vector_type(4)));
typedef unsigned short ushort8_t __attribute__((ext_vector_type(8)));
typedef unsigned long long u64;

#if __has_builtin(__builtin_amdgcn_exp2f)
#define EXP2(x) __builtin_amdgcn_exp2f(x)
#else
#define EXP2(x) exp2f(x)
#endif

static __device__ __forceinline__ unsigned short bfb(float f) {
    bf16 h = (bf16)f;  // RNE
    return __builtin_bit_cast(unsigned short, h);
}
// kv' bit-permutation: kv bits [b5 b4 b3 b2 b1 b0] -> kv' = [b5 b3 b2 b4 b1 b0].
static __device__ __forceinline__ int phi_inv(int c) {
    return ((c >> 5) & 1) * 32 + ((c >> 2) & 1) * 16 + ((c >> 4) & 1) * 8 +
           ((c >> 3) & 1) * 4 + (c & 3);
}
static __device__ __forceinline__ void gload16(const unsigned short* g, unsigned short* l) {
    __builtin_amdgcn_global_load_lds(
        (const __attribute__((address_space(1))) unsigned int*)g,
        (__attribute__((address_space(3))) unsigned int*)l, 16, 0, 0);
}

#define KV_BLOCKS (B_ * H_ * NT)  // 2048

// Fused prepass: blocks [0, KV_BLOCKS) convert K/V (if Ko != null); rest bitpack mask.
__global__ __launch_bounds__(256) void prep_fused(
    const float* __restrict__ K, const float* __restrict__ V,
    unsigned short* __restrict__ Ko, unsigned short* __restrict__ Vo,
    const int* __restrict__ M, u64* __restrict__ W) {
    const int tid = threadIdx.x;
    if (blockIdx.x >= KV_BLOCKS) {
        const int ln = tid & 63;
        const int w0 = (blockIdx.x - KV_BLOCKS) * 32 + (tid >> 6) * 8;
#pragma unroll
        for (int j = 0; j < 8; ++j) {
            const int v = M[(long)(w0 + j) * 64 + ln];
            const u64 bal = __ballot(v != 0);
            if (ln == 0) W[w0 + j] = bal;
        }
        return;
    }
    if (Ko == nullptr) return;
    __shared__ float Vl[64][65];
    const int t = blockIdx.x & (NT - 1);
    const int bh = blockIdx.x >> 5;
    const float* Kg = K + ((long)bh * S_ + t * 64) * D_;
    const float* Vg = V + ((long)bh * S_ + t * 64) * D_;
    unsigned short* Kout = Ko + ((long)bh * S_ + t * 64) * D_;
    unsigned short* Vout = Vo + (long)bh * D_ * S_ + t * 64;
    {   // K convert: 16 elems/thread
        const int kv = tid >> 2, d0 = (tid & 3) * 16;
#pragma unroll
        for (int half = 0; half < 2; ++half) {
            const float4 f0 = *(const float4*)(Kg + kv * D_ + d0 + half * 8);
            const float4 f1 = *(const float4*)(Kg + kv * D_ + d0 + half * 8 + 4);
            ushort8_t u;
            u[0] = bfb(f0.x); u[1] = bfb(f0.y); u[2] = bfb(f0.z); u[3] = bfb(f0.w);
            u[4] = bfb(f1.x); u[5] = bfb(f1.y); u[6] = bfb(f1.z); u[7] = bfb(f1.w);
            *(ushort8_t*)(Kout + kv * D_ + d0 + half * 8) = u;
        }
    }
    {   // V stage to LDS (coalesced reads)
#pragma unroll
        for (int i = 0; i < 4; ++i) {
            const int kv = i * 16 + (tid >> 4);
            const int d4 = (tid & 15) * 4;
            const float4 f = *(const float4*)(Vg + kv * D_ + d4);
            Vl[kv][d4 + 0] = f.x; Vl[kv][d4 + 1] = f.y;
            Vl[kv][d4 + 2] = f.z; Vl[kv][d4 + 3] = f.w;
        }
    }
    __syncthreads();
    {   // write transposed+permuted, coalesced ushort4 stores
#pragma unroll
        for (int j = 0; j < 4; ++j) {
            const int chunk = j * 256 + tid;
            const int d = chunk >> 4, q4 = chunk & 15;
            ushort4 w;
            w.x = bfb(Vl[phi_inv(q4 * 4 + 0)][d]);
            w.y = bfb(Vl[phi_inv(q4 * 4 + 1)][d]);
            w.z = bfb(Vl[phi_inv(q4 * 4 + 2)][d]);
            w.w = bfb(Vl[phi_inv(q4 * 4 + 3)][d]);
            *(ushort4*)(Vout + (long)d * S_ + q4 * 4) = w;
        }
    }
}

// ---- main kernel. MODE: 2=preconv+gload_lds pipeline, 1=reg-stage+bits, 0=reg-stage+raw ----
template <int MODE>
__global__ __launch_bounds__(512, 4) void attn_fwd(
    const float* __restrict__ Q, const float* __restrict__ K,
    const float* __restrict__ V, const int* __restrict__ M,
    const u64* __restrict__ W, const unsigned short* __restrict__ Kp,
    const unsigned short* __restrict__ Vp, float* __restrict__ O)
{
    __shared__ __attribute__((aligned(16))) unsigned short Ks3[4 * TILE_E];  // 32 KB
    __shared__ __attribute__((aligned(16))) unsigned short Vt3[4 * TILE_E];  // 32 KB

    const int tid = threadIdx.x;
    const int wv = tid >> 6, ln = tid & 63;
    const int col = ln & 15, grp = ln >> 4;

    int bid = blockIdx.x;
    bid = (bid & 7) * 128 + (bid >> 3);  // XCD chunk swizzle (1024 % 8 == 0, bijective)
    const int qt = bid & 15;
    const int h = (bid >> 4) & 7;
    const int b = bid >> 7;
    const int qw = qt * QT + wv * 16;

    // Q frag (B-operand): lane holds Q[q=col][d = c*32+grp*8+j] * QSCALE
    const float* Qg = Q + ((long)((b * H_ + h) * S_) + qw + col) * D_;
    bf16x8 qf[2];
#pragma unroll
    for (int c = 0; c < 2; ++c) {
        const float4 a0 = *(const float4*)(Qg + c * 32 + grp * 8);
        const float4 a1 = *(const float4*)(Qg + c * 32 + grp * 8 + 4);
        qf[c][0] = (bf16)(a0.x * QSCALE); qf[c][1] = (bf16)(a0.y * QSCALE);
        qf[c][2] = (bf16)(a0.z * QSCALE); qf[c][3] = (bf16)(a0.w * QSCALE);
        qf[c][4] = (bf16)(a1.x * QSCALE); qf[c][5] = (bf16)(a1.y * QSCALE);
        qf[c][6] = (bf16)(a1.z * QSCALE); qf[c][7] = (bf16)(a1.w * QSCALE);
    }
    bf16x8 onesf;
#pragma unroll
    for (int j = 0; j < 8; ++j) onesf[j] = (bf16)1.0f;
    const f32x4 zq = (f32x4){0.f, 0.f, 0.f, 0.f};  // persistent zero C-in

    f32x4 oacc[4];
#pragma unroll
    for (int i = 0; i < 4; ++i) oacc[i] = zq;
    f32x4 accs = zq;  // accs[r] = denominator for q=grp*4+r

    const u64* Wg = (MODE >= 1) ? (W + ((long)b * S_ + qw + col) * (S_ / 64)) : nullptr;
    const int* Mg = (MODE == 0) ? (M + ((long)b * S_ + qw + col) * S_) : nullptr;
    const unsigned short* Kbh = Kp + (long)(b * H_ + h) * S_ * D_;
    const unsigned short* Vbh = Vp + (long)(b * H_ + h) * D_ * S_;
    const float* Kf = K + (long)(b * H_ + h) * S_ * D_;
    const float* Vf = V + (long)(b * H_ + h) * S_ * D_;

    // MODE2 gload addressing: inverse-swizzled global source, linear LDS dest
    const int rl = ln >> 3;
    const int c8 = (ln & 7) ^ rl;
    const int krow = wv * 8 + rl;

    // MODE<=1 reg staging state
    float4 ka[2];
    float va[8];
    const int vd = ln, kg0 = wv;

    auto STAGE_ISSUE = [&](int kv0, int buf) {  // MODE2: 2 gload_lds/thread
        gload16(Kbh + (long)(kv0 + krow) * D_ + c8 * 8, Ks3 + buf * TILE_E + wv * 512);
        gload16(Vbh + (long)krow * S_ + kv0 + c8 * 8, Vt3 + buf * TILE_E + wv * 512);
    };
    auto LOADT = [&](int kv0) {  // MODE<=1
#pragma unroll
        for (int i = 0; i < 2; ++i) {
            const int idx4 = i * 512 + tid;
            const int row = idx4 >> 4, c4 = idx4 & 15;
            ka[i] = *(const float4*)(Kf + (long)(kv0 + row) * D_ + c4 * 4);
        }
#pragma unroll
        for (int i = 0; i < 2; ++i) {
            const int kg = kg0 + i * 8;
            const int kvn = phi_inv(kg * 4);
#pragma unroll
            for (int j = 0; j < 4; ++j)
                va[i * 4 + j] = Vf[(long)(kv0 + kvn + j) * D_ + vd];
        }
    };
    auto WRITET = [&](int buf) {  // MODE<=1
#pragma unroll
        for (int i = 0; i < 2; ++i) {
            const int idx4 = i * 512 + tid;
            const int row = idx4 >> 4, c4 = idx4 & 15;
            const int byte = (row * 128 + c4 * 8) ^ ((row & 7) << 4);
            ushort4 w;
            w.x = bfb(ka[i].x); w.y = bfb(ka[i].y);
            w.z = bfb(ka[i].z); w.w = bfb(ka[i].w);
            *(ushort4*)((char*)(Ks3 + buf * TILE_E) + byte) = w;
        }
#pragma unroll
        for (int i = 0; i < 2; ++i) {
            const int kg = kg0 + i * 8;
            const int byte = (vd * 128 + kg * 8) ^ ((vd & 7) << 4);
            ushort4 w;
            w.x = bfb(va[i * 4 + 0]); w.y = bfb(va[i * 4 + 1]);
            w.z = bfb(va[i * 4 + 2]); w.w = bfb(va[i * 4 + 3]);
            *(ushort4*)((char*)(Vt3 + buf * TILE_E) + byte) = w;
        }
    };

    // STEP: mask word preloaded (MODE>=1) or raw-mask t (MODE 0)
    auto STEP = [&](u64 mwfull, int t, const unsigned short* Kc, const unsigned short* Vc) {
        f32x4 sc[4];
        __builtin_amdgcn_s_setprio(1);
#pragma unroll
        for (int blk = 0; blk < 4; ++blk) {
            const int row = blk * 16 + col;
            const int byte0 = (row * 128 + grp * 16) ^ ((row & 7) << 4);
            const int byte1 = (row * 128 + 64 + grp * 16) ^ ((row & 7) << 4);
            const bf16x8 kf0 = *(const bf16x8*)((const char*)Kc + byte0);
            const bf16x8 kf1 = *(const bf16x8*)((const char*)Kc + byte1);
            sc[blk] = __builtin_amdgcn_mfma_f32_16x16x32_bf16(kf0, qf[0], zq, 0, 0, 0);
            sc[blk] = __builtin_amdgcn_mfma_f32_16x16x32_bf16(kf1, qf[1], sc[blk], 0, 0, 0);
        }
        __builtin_amdgcn_s_setprio(0);
        // select + exp2 + bf16 pack (no max subtraction; masked -> exp2(-1e9)=0)
        bf16x8 pf[2];
        if (MODE >= 1) {
            const u64 mws = mwfull >> (grp * 4);
            const unsigned mlo = (unsigned)mws, mhi = (unsigned)(mws >> 32);
#pragma unroll
            for (int c = 0; c < 2; ++c)
#pragma unroll
                for (int j = 0; j < 8; ++j) {
                    const int blk = 2 * c + (j >> 2), r = j & 3;
                    const unsigned w32 = (blk < 2) ? mlo : mhi;
                    const int bit = (blk & 1) * 16 + r;  // compile-time
                    const float s = ((w32 >> bit) & 1u) ? sc[blk][r] : -1e9f;
                    pf[c][j] = (bf16)EXP2(s);
                }
        } else {
#pragma unroll
            for (int c = 0; c < 2; ++c)
#pragma unroll
                for (int j = 0; j < 8; ++j) {
                    const int blk = 2 * c + (j >> 2), r = j & 3;
                    const int mv = Mg[t * KT + blk * 16 + grp * 4 + r];
                    const float s = mv ? sc[blk][r] : -1e9f;
                    pf[c][j] = (bf16)EXP2(s);
                }
        }
        // denominator + PV via MFMA
        __builtin_amdgcn_s_setprio(1);
        accs = __builtin_amdgcn_mfma_f32_16x16x32_bf16(pf[0], onesf, accs, 0, 0, 0);
        accs = __builtin_amdgcn_mfma_f32_16x16x32_bf16(pf[1], onesf, accs, 0, 0, 0);
#pragma unroll
        for (int c = 0; c < 2; ++c)
#pragma unroll
            for (int db = 0; db < 4; ++db) {
                const int vrow = db * 16 + col;
                const int byte = (vrow * 128 + c * 64 + grp * 16) ^ ((vrow & 7) << 4);
                const bf16x8 vf = *(const bf16x8*)((const char*)Vc + byte);
                oacc[db] = __builtin_amdgcn_mfma_f32_16x16x32_bf16(pf[c], vf, oacc[db], 0, 0, 0);
            }
        __builtin_amdgcn_s_setprio(0);
    };

#define WAIT2_BAR() do { asm volatile("s_waitcnt vmcnt(2)" ::: "memory"); \
    __builtin_amdgcn_s_barrier(); __builtin_amdgcn_sched_barrier(0); } while (0)
#define WAIT0_BAR() do { asm volatile("s_waitcnt vmcnt(0)" ::: "memory"); \
    __builtin_amdgcn_s_barrier(); __builtin_amdgcn_sched_barrier(0); } while (0)

    if (MODE == 2) {
        // ---- depth-2 pipeline: stage t+2 while computing t; vmcnt(2) barriers ----
        STAGE_ISSUE(0, 0);
        STAGE_ISSUE(KT, 1);
        WAIT2_BAR();  // tile 0 ready; tile 1 may still be in flight
#pragma unroll 1
        for (int tt = 0; tt + 4 < NT; tt += 4) {  // t = 0 .. 27
#pragma unroll
            for (int j = 0; j < 4; ++j) {
                const int t = tt + j;
                const u64 mw = Wg[t];                       // before STAGE: waitable at vmcnt(2)
                STAGE_ISSUE((t + 2) * KT, (j + 2) & 3);     // compile-time buf
                STEP(mw, t, Ks3 + j * TILE_E, Vt3 + j * TILE_E);
                WAIT2_BAR();                                // t+1 ready, t+2 stays in flight
            }
        }
        {   // tail: t = NT-4 .. NT-1 (28..31)
            const u64 mw0 = Wg[NT - 4];
            STAGE_ISSUE((NT - 2) * KT, (NT - 2) & 3);
            STEP(mw0, NT - 4, Ks3 + ((NT - 4) & 3) * TILE_E, Vt3 + ((NT - 4) & 3) * TILE_E);
            WAIT2_BAR();
            const u64 mw1 = Wg[NT - 3];
            STAGE_ISSUE((NT - 1) * KT, (NT - 1) & 3);
            STEP(mw1, NT - 3, Ks3 + ((NT - 3) & 3) * TILE_E, Vt3 + ((NT - 3) & 3) * TILE_E);
            WAIT2_BAR();
            const u64 mw2 = Wg[NT - 2];
            STEP(mw2, NT - 2, Ks3 + ((NT - 2) & 3) * TILE_E, Vt3 + ((NT - 2) & 3) * TILE_E);
            WAIT0_BAR();
            const u64 mw3 = Wg[NT - 1];
            STEP(mw3, NT - 1, Ks3 + ((NT - 1) & 3) * TILE_E, Vt3 + ((NT - 1) & 3) * TILE_E);
        }
    } else {
        // ---- fallback: 2-buffer, __syncthreads ----
        LOADT(0);
        WRITET(0);
        __syncthreads();
#pragma unroll 1
        for (int t = 0; t < NT; t += 2) {
            if (t + 1 < NT) LOADT((t + 1) * KT);
            STEP(MODE >= 1 ? Wg[t] : 0ull, t, Ks3, Vt3);
            if (t + 1 < NT) WRITET(1);
            __syncthreads();
            if (t + 2 < NT) LOADT((t + 2) * KT);
            STEP(MODE >= 1 ? Wg[t + 1] : 0ull, t + 1, Ks3 + TILE_E, Vt3 + TILE_E);
            if (t + 2 < NT) WRITET(0);
            __syncthreads();
        }
    }

    // epilogue: accs[r] is the denominator, same layout as oacc — no shuffles
    float* Og = O + ((long)((b * H_ + h) * S_) + qw) * D_;
#pragma unroll
    for (int r = 0; r < 4; ++r) {
        const float inv = 1.0f / accs[r];
#pragma unroll
        for (int db = 0; db < 4; ++db)
            Og[(grp * 4 + r) * D_ + db * 16 + col] = oacc[db][r] * inv;
    }
#undef WAIT2_BAR
#undef WAIT0_BAR
}

extern "C" void kernel_launch(void* const* d_in, const int* in_sizes, int n_in,
                              void* d_out, int out_size, void* d_ws, size_t ws_size,
                              hipStream_t stream) {
    (void)in_sizes; (void)n_in; (void)out_size;
    const float* Q = (const float*)d_in[0];
    const float* K = (const float*)d_in[1];
    const float* V = (const float*)d_in[2];
    const int*   M = (const int*)d_in[3];
    float* O = (float*)d_out;

    const size_t szW = (size_t)B_ * S_ * (S_ / 64) * sizeof(u64);      // 4 MB
    const size_t szK = (size_t)B_ * H_ * S_ * D_ * 2;                  // 16 MB
    const int grid = B_ * H_ * (S_ / QT);                              // 1024
    const int nmaskblk = (B_ * S_ * (S_ / 64)) / 32;                   // 16384

    if (ws_size >= szW + 2 * szK) {
        u64* W = (u64*)d_ws;
        unsigned short* Kp = (unsigned short*)((char*)d_ws + szW);
        unsigned short* Vp = (unsigned short*)((char*)d_ws + szW + szK);
        prep_fused<<<KV_BLOCKS + nmaskblk, 256, 0, stream>>>(K, V, Kp, Vp, M, W);
        attn_fwd<2><<<grid, 512, 0, stream>>>(Q, K, V, M, W, Kp, Vp, O);
    } else if (ws_size >= szW) {
        u64* W = (u64*)d_ws;
        prep_fused<<<KV_BLOCKS + nmaskblk, 256, 0, stream>>>(K, V, nullptr, nullptr, M, W);
        attn_fwd<1><<<grid, 512, 0, stream>>>(Q, K, V, M, W, nullptr, nullptr, O);
    } else {
        attn_fwd<0><<<grid, 512, 0, stream>>>(Q, K, V, M, nullptr, nullptr, nullptr, O);
    }
}